// Round 4
// baseline (3666.928 us; speedup 1.0000x reference)
//
#include <hip/hip_runtime.h>
#include <hip/hip_bf16.h>

typedef __hip_bfloat16 bf16;

#define NA    4096
#define NM    16384

__device__ __forceinline__ float b2f(bf16 v) { return __bfloat162float(v); }

__device__ __forceinline__ float ldw(const void* p, size_t i, int bf) {
    if (bf) return b2f(((const bf16*)p)[i]);
    return ((const float*)p)[i];
}

__device__ __forceinline__ bf16 f2b(float f) {
    union { unsigned u; float ff; } cv; cv.ff = f;
    unsigned r = (cv.u + 0x7FFFu + ((cv.u >> 16) & 1u)) >> 16;
    unsigned short us = (unsigned short)r;
    bf16 out; __builtin_memcpy(&out, &us, 2);
    return out;
}

// ---------------- dtype probe: bf16 vs f32 float buffers ----------------
__global__ void k_flag(const void* __restrict__ fnode, int* __restrict__ flag) {
    if (threadIdx.x == 0 && blockIdx.x == 0) {
        const unsigned short* u = (const unsigned short*)fnode;
        int cnt = 0;
        for (int i = 0; i < 64; i++) {
            unsigned short us = u[2 * i];
            unsigned ex = (us >> 7) & 0xFF;
            if (us == 0 || (ex >= 105 && ex <= 134)) cnt++;
        }
        *flag = (cnt >= 48) ? 1 : 0;
    }
}

// ---------------- cast fnode -> f32 ----------------
__global__ void k_cast(const void* __restrict__ in, float* __restrict__ out, int n,
                       const int* __restrict__ flag) {
    int bf = *flag;
    int i = blockIdx.x * 256 + threadIdx.x;
    if (i < n) out[i] = ldw(in, i, bf);
}

// ---------------- GEMM: C[4096 x 256] = A[4096 x K] * W[256 x K]^T (+bias) ----------------
__global__ __launch_bounds__(256) void k_gemm_nt(
    const float* __restrict__ A, const void* __restrict__ W, size_t woff,
    const void* __restrict__ bias, size_t boff, int has_bias,
    float* __restrict__ C, int K, const int* __restrict__ flag)
{
    int bf = *flag;
    __shared__ float Wl[256 * 33];
    __shared__ float Al[32 * 20];
    int a0 = blockIdx.x * 16;
    int c  = threadIdx.x;
    float acc[16];
#pragma unroll
    for (int i = 0; i < 16; i++) acc[i] = 0.f;

    for (int k0 = 0; k0 < K; k0 += 32) {
        __syncthreads();
        for (int i = threadIdx.x; i < 256 * 32; i += 256) {
            int c2 = i >> 5, kk = i & 31, k = k0 + kk;
            Wl[c2 * 33 + kk] = (k < K) ? ldw(W, woff + (size_t)c2 * K + k, bf) : 0.f;
        }
        for (int i = threadIdx.x; i < 512; i += 256) {
            int aa = i >> 5, kk = i & 31, k = k0 + kk;
            Al[kk * 20 + aa] = (k < K) ? A[(size_t)(a0 + aa) * K + k] : 0.f;
        }
        __syncthreads();
#pragma unroll
        for (int kk = 0; kk < 32; kk++) {
            float w = Wl[c * 33 + kk];
            const float4* ap = (const float4*)&Al[kk * 20];
            float4 a01 = ap[0], a23 = ap[1], a45 = ap[2], a67 = ap[3];
            acc[0]  += a01.x * w; acc[1]  += a01.y * w; acc[2]  += a01.z * w; acc[3]  += a01.w * w;
            acc[4]  += a23.x * w; acc[5]  += a23.y * w; acc[6]  += a23.z * w; acc[7]  += a23.w * w;
            acc[8]  += a45.x * w; acc[9]  += a45.y * w; acc[10] += a45.z * w; acc[11] += a45.w * w;
            acc[12] += a67.x * w; acc[13] += a67.y * w; acc[14] += a67.z * w; acc[15] += a67.w * w;
        }
    }
    float bv = has_bias ? ldw(bias, boff + c, bf) : 0.f;
#pragma unroll
    for (int i = 0; i < 16; i++) C[(size_t)(a0 + i) * 256 + c] = acc[i] + bv;
}

// ---------------- transpose x (4096x256) -> xT (256x4096) ----------------
__global__ __launch_bounds__(256) void k_xpose(const float* __restrict__ x, float* __restrict__ xT) {
    __shared__ float tl[32][33];
    int bx = blockIdx.x, by = blockIdx.y;
    int tx = threadIdx.x & 31, ty = threadIdx.x >> 5;
#pragma unroll
    for (int i = 0; i < 4; i++)
        tl[ty + i * 8][tx] = x[(size_t)(bx * 32 + ty + i * 8) * 256 + by * 32 + tx];
    __syncthreads();
#pragma unroll
    for (int i = 0; i < 4; i++)
        xT[(size_t)(by * 32 + ty + i * 8) * NA + bx * 32 + tx] = tl[tx][ty + i * 8];
}

// ---------------- build transposed hmess (tiled, coalesced both sides) ----------------
// grid (NM/32, 9); block 256. hmT[k][m], k<288 (262 valid, zero-padded)
__global__ __launch_bounds__(256) void k_hmess_t(
    const float* __restrict__ x, const void* __restrict__ fmess,
    float* __restrict__ hmT, const int* __restrict__ flag)
{
    int bf = *flag;
    const int mb = blockIdx.x * 32;
    const int kc = blockIdx.y;     // 0..8
    const int k0 = kc * 32;
    __shared__ float tl[32][33];
    __shared__ int srcs[32];
    const int tid = threadIdx.x;
    if (tid < 32) {
        int s = (int)ldw(fmess, (size_t)(mb + tid) * 8, bf);
        srcs[tid] = min(max(s, 0), NA - 1);
    }
    __syncthreads();
    {
        const int ml = tid >> 3, kg = (tid & 7) * 4;
        if (kc < 8) {
            const float4 v = *(const float4*)&x[(size_t)srcs[ml] * 256 + k0 + kg];
            tl[ml][kg] = v.x; tl[ml][kg + 1] = v.y; tl[ml][kg + 2] = v.z; tl[ml][kg + 3] = v.w;
        } else {
#pragma unroll
            for (int j = 0; j < 4; j++) {
                int k = k0 + kg + j;
                float v = (k < 262) ? ldw(fmess, (size_t)(mb + ml) * 8 + 2 + (k - 256), bf) : 0.f;
                tl[ml][kg + j] = v;
            }
        }
    }
    __syncthreads();
    {
        const int kl = tid >> 3, mg = (tid & 7) * 4;
        float4 w;
        w.x = tl[mg][kl]; w.y = tl[mg + 1][kl]; w.z = tl[mg + 2][kl]; w.w = tl[mg + 3][kl];
        *(float4*)&hmT[(size_t)(k0 + kl) * NM + mb + mg] = w;
    }
}

// ---------------- mol membership map ----------------
__global__ void k_molmap(const int* __restrict__ scopes, int nmol, int* __restrict__ molid) {
    int a = blockIdx.x * 256 + threadIdx.x;
    if (a >= NA) return;
    int mid = -1;
    for (int s2 = 0; s2 < nmol; s2++) {
        int st = scopes[2 * s2], ln = scopes[2 * s2 + 1];
        if (a >= st && a < st + ln) mid = s2;
    }
    molid[a] = mid;
}

// ---------------- precompute r1/az/ah for a chunk of tch t's ----------------
// grid (NM/512, tch, 4 dsub); block 256; 2 msgs/lane.  Output layout [(ti*32+d)*NM + m].
__global__ __launch_bounds__(256) void k_pre(
    const float* __restrict__ hmT,
    const void* __restrict__ Wr_w, const void* __restrict__ Wz_w, const void* __restrict__ Wh_w,
    const void* __restrict__ Ur_b, const void* __restrict__ Wz_b, const void* __restrict__ Wh_b,
    int t0, float* __restrict__ r1, float* __restrict__ az, float* __restrict__ ah,
    const int* __restrict__ flag)
{
    int bf = *flag;
    const int ti = blockIdx.y, t = t0 + ti, dsub = blockIdx.z;
    __shared__ float WL[3][8][288];
    for (int i = threadIdx.x; i < 3 * 8 * 288; i += 256) {
        int mt = i / 2304, rr = i - mt * 2304, dj = rr / 288, k = rr - dj * 288;
        int d = dsub * 8 + dj;
        float v = 0.f;
        if (k < 262) {
            if (mt == 0)      v = ldw(Wr_w, ((size_t)t * 32 + d) * 262 + k, bf);
            else if (mt == 1) v = ldw(Wz_w, ((size_t)t * 32 + d) * 294 + k, bf);
            else              v = ldw(Wh_w, ((size_t)t * 32 + d) * 294 + k, bf);
        }
        WL[mt][dj][k] = v;
    }
    __syncthreads();
    int m0 = blockIdx.x * 512 + threadIdx.x;
    int m1 = m0 + 256;
    float aR0[8] = {}, aZ0[8] = {}, aH0[8] = {}, aR1[8] = {}, aZ1[8] = {}, aH1[8] = {};
    for (int kc = 0; kc < 9; kc++) {
        int k0 = kc * 32;
        float hv0[32], hv1[32];
#pragma unroll
        for (int kk = 0; kk < 32; kk++) {
            hv0[kk] = hmT[(size_t)(k0 + kk) * NM + m0];
            hv1[kk] = hmT[(size_t)(k0 + kk) * NM + m1];
        }
#pragma unroll
        for (int dj = 0; dj < 8; dj++) {
#pragma unroll
            for (int kk = 0; kk < 32; kk += 4) {
                float4 wr = *(const float4*)&WL[0][dj][k0 + kk];
                float4 wz = *(const float4*)&WL[1][dj][k0 + kk];
                float4 wh = *(const float4*)&WL[2][dj][k0 + kk];
                aR0[dj] += hv0[kk] * wr.x + hv0[kk + 1] * wr.y + hv0[kk + 2] * wr.z + hv0[kk + 3] * wr.w;
                aR1[dj] += hv1[kk] * wr.x + hv1[kk + 1] * wr.y + hv1[kk + 2] * wr.z + hv1[kk + 3] * wr.w;
                aZ0[dj] += hv0[kk] * wz.x + hv0[kk + 1] * wz.y + hv0[kk + 2] * wz.z + hv0[kk + 3] * wz.w;
                aZ1[dj] += hv1[kk] * wz.x + hv1[kk + 1] * wz.y + hv1[kk + 2] * wz.z + hv1[kk + 3] * wz.w;
                aH0[dj] += hv0[kk] * wh.x + hv0[kk + 1] * wh.y + hv0[kk + 2] * wh.z + hv0[kk + 3] * wh.w;
                aH1[dj] += hv1[kk] * wh.x + hv1[kk + 1] * wh.y + hv1[kk + 2] * wh.z + hv1[kk + 3] * wh.w;
            }
        }
    }
#pragma unroll
    for (int dj = 0; dj < 8; dj++) {
        int d = dsub * 8 + dj;
        size_t row = (size_t)(ti * 32 + d) * NM;
        float rb  = ldw(Ur_b, t * 32 + d, bf);
        float zb  = ldw(Wz_b, t * 32 + d, bf);
        float hb2 = ldw(Wh_b, t * 32 + d, bf);
        r1[row + m0] = aR0[dj] + rb;  r1[row + m1] = aR1[dj] + rb;
        az[row + m0] = aZ0[dj] + zb;  az[row + m1] = aZ1[dj] + zb;
        ah[row + m0] = aH0[dj] + hb2; ah[row + m1] = aH1[dj] + hb2;
    }
}

// ---------------- depth-1 GRU step (h_in == 0): h = sigmoid(az)*tanh(ah)*mask ----------------
// grid (NM/64, tch); block 256 = 64 messages x 4 d-quarters
__global__ __launch_bounds__(256) void k_step0(
    const float* __restrict__ az, const float* __restrict__ ah, float* __restrict__ h_out)
{
    const int ti = blockIdx.y;
    __shared__ float tb[4][16 * 33];
    const int q = threadIdx.x & 3, ml = threadIdx.x >> 2;
    const int m = blockIdx.x * 64 + ml;
    const int d0 = q * 8;
    const int wv = threadIdx.x >> 6, l = threadIdx.x & 63, mw = ml & 15;
    float msk_m = (m == 0) ? 0.f : 1.f;
#pragma unroll
    for (int dd = 0; dd < 8; dd++) {
        int d = d0 + dd;
        float zacc = az[(size_t)(ti * 32 + d) * NM + m];
        float pacc = ah[(size_t)(ti * 32 + d) * NM + m];
        float zz = 1.f / (1.f + __expf(-zacc));
        float cl = fminf(fmaxf(pacc, -20.f), 20.f);
        float e2 = __expf(2.f * cl);
        float th = (e2 - 1.f) / (e2 + 1.f);
        tb[wv][mw * 33 + d] = zz * th * msk_m;
    }
    __syncthreads();
    float* ho = h_out + (size_t)ti * NM * 32 + ((size_t)blockIdx.x * 64 + wv * 16) * 32;
#pragma unroll
    for (int i = 0; i < 8; i++) {
        int idx = i * 64 + l;
        int mm = idx >> 5, d = idx & 31;
        ho[idx] = tb[wv][mm * 33 + d];
    }
}

// ---------------- full GRU depth step ----------------
// 1-D grid 256*tch, XCD-swizzled so each XCD's gathers stay in one h ti-slice.
// block 256 = 64 messages x 4 d-quarters; h layout [(ti*NM+m)*32+d]
__global__ __launch_bounds__(256, 4) void k_step(
    const float* __restrict__ h_in, float* __restrict__ h_out,
    const float* __restrict__ r1, const float* __restrict__ az, const float* __restrict__ ah,
    const int* __restrict__ bgraph,
    const void* __restrict__ Ur_w, const void* __restrict__ Wz_w, const void* __restrict__ Wh_w,
    int t0, int tch, const int* __restrict__ flag)
{
    int bf = *flag;
    const int wgid = blockIdx.x;
    const int g = wgid & 7, sIdx = wgid >> 3;
    const int work = g * (tch * 32) + sIdx;     // ti-major: one XCD ~ one ti slice
    const int ti = work >> 8;
    const int xb = work & 255;
    const int t = t0 + ti;
    __shared__ float UrL[32 * 37], WzL[32 * 37], WhL[32 * 37];   // pad 37: q-groups on distinct banks
    __shared__ float tb[4][16 * 33];
    for (int i = threadIdx.x; i < 32 * 37; i += 256) {
        int d = i / 37, j = i - d * 37;
        float u = 0.f, wz = 0.f, wh = 0.f;
        if (j < 32) {
            u  = ldw(Ur_w, ((size_t)t * 32 + d) * 32 + j, bf);
            wz = ldw(Wz_w, ((size_t)t * 32 + d) * 294 + 262 + j, bf);
            wh = ldw(Wh_w, ((size_t)t * 32 + d) * 294 + 262 + j, bf);
        }
        UrL[i] = u; WzL[i] = wz; WhL[i] = wh;
    }
    __syncthreads();
    const int q  = threadIdx.x & 3;
    const int ml = threadIdx.x >> 2;
    const int m  = xb * 64 + ml;
    const int d0 = q * 8;
    const float* hb = h_in + (size_t)ti * NM * 32;

    float r1v[8];
#pragma unroll
    for (int dd = 0; dd < 8; dd++)
        r1v[dd] = r1[(size_t)(ti * 32 + d0 + dd) * NM + m];

    float sumh[8], rh[8];
#pragma unroll
    for (int dd = 0; dd < 8; dd++) { sumh[dd] = 0.f; rh[dd] = 0.f; }

#pragma unroll
    for (int nb = 0; nb < 6; nb++) {
        int bg = bgraph[m * 6 + nb];
        bg = min(max(bg, 0), NM - 1);
        const float* hr = hb + (size_t)bg * 32;
        float hc[32];
#pragma unroll
        for (int j4 = 0; j4 < 32; j4 += 4) {
            float4 v = *(const float4*)&hr[j4];
            hc[j4] = v.x; hc[j4 + 1] = v.y; hc[j4 + 2] = v.z; hc[j4 + 3] = v.w;
        }
        float4 o1 = *(const float4*)&hr[d0];
        float4 o2 = *(const float4*)&hr[d0 + 4];
        float hown[8] = {o1.x, o1.y, o1.z, o1.w, o2.x, o2.y, o2.z, o2.w};
#pragma unroll
        for (int dd = 0; dd < 8; dd++) {
            float acc = r1v[dd];
            const float* ur = &UrL[(d0 + dd) * 37];
#pragma unroll
            for (int j = 0; j < 32; j++) acc += hc[j] * ur[j];
            float rr = 1.f / (1.f + __expf(-acc));
            sumh[dd] += hown[dd];
            rh[dd] += rr * hown[dd];
        }
    }
    float recvS[4][8], recvH[4][8];
#pragma unroll
    for (int e = 0; e < 4; e++)
#pragma unroll
        for (int jj = 0; jj < 8; jj++) {
            recvS[e][jj] = __shfl_xor(sumh[jj], e, 4);
            recvH[e][jj] = __shfl_xor(rh[jj], e, 4);
        }
    float msk_m = (m == 0) ? 0.f : 1.f;
    const int wv = threadIdx.x >> 6, l = threadIdx.x & 63, mw = ml & 15;
#pragma unroll
    for (int dd = 0; dd < 8; dd++) {
        int d = d0 + dd;
        float zacc = az[(size_t)(ti * 32 + d) * NM + m];
        float pacc = ah[(size_t)(ti * 32 + d) * NM + m];
#pragma unroll
        for (int e = 0; e < 4; e++) {
            int jb = (q ^ e) * 8;
            const float* wz = &WzL[d * 37 + jb];
            const float* wh = &WhL[d * 37 + jb];
#pragma unroll
            for (int jj = 0; jj < 8; jj++) {
                zacc += recvS[e][jj] * wz[jj];
                pacc += recvH[e][jj] * wh[jj];
            }
        }
        float zz = 1.f / (1.f + __expf(-zacc));
        float cl = fminf(fmaxf(pacc, -20.f), 20.f);
        float e2 = __expf(2.f * cl);
        float th = (e2 - 1.f) / (e2 + 1.f);
        tb[wv][mw * 33 + d] = ((1.f - zz) * sumh[dd] + zz * th) * msk_m;
    }
    __syncthreads();
    float* ho = h_out + (size_t)ti * NM * 32 + ((size_t)xb * 64 + wv * 16) * 32;
#pragma unroll
    for (int i = 0; i < 8; i++) {
        int idx = i * 64 + l;
        int mm = idx >> 5, d = idx & 31;
        ho[idx] = tb[wv][mm * 33 + d];
    }
}

// ---------------- outs = relu([x, nei] @ Wo^T + b) * node_mask, scattered into qkv ----------------
// 1-D grid 64*tch, XCD-swizzled; block 256 = 64 atoms x 4 d-quarters
__global__ __launch_bounds__(256) void k_outs(
    const float* __restrict__ xT, const float* __restrict__ h,
    const int* __restrict__ agraph, const void* __restrict__ Wo_w, const void* __restrict__ Wo_b,
    int t0, int tch, float* __restrict__ qkv, const int* __restrict__ flag)
{
    int bf = *flag;
    const int wgid = blockIdx.x;
    const int g = wgid & 7, sIdx = wgid >> 3;
    const int work = g * (tch * 8) + sIdx;
    const int ti = work >> 6;
    const int xb = work & 63;
    const int t = t0 + ti;
    const int hh = t / 3, s2 = t - 3 * hh;
    __shared__ float WL[32 * 297];
    __shared__ float tb[4][16 * 33];
    for (int i = threadIdx.x; i < 32 * 297; i += 256) {
        int d = i / 297, k = i - d * 297;
        WL[i] = (k < 288) ? ldw(Wo_w, ((size_t)t * 32 + d) * 288 + k, bf) : 0.f;
    }
    __syncthreads();
    const int q = threadIdx.x & 3, al = threadIdx.x >> 2;
    const int a = xb * 64 + al;
    const int d0 = q * 8;
    float nei[32];
#pragma unroll
    for (int j = 0; j < 32; j++) nei[j] = 0.f;
#pragma unroll
    for (int nb = 0; nb < 6; nb++) {
        int ag = agraph[a * 6 + nb];
        ag = min(max(ag, 0), NM - 1);
        const float* hr = h + ((size_t)ti * NM + ag) * 32;
#pragma unroll
        for (int j4 = 0; j4 < 32; j4 += 4) {
            float4 v = *(const float4*)&hr[j4];
            nei[j4] += v.x; nei[j4 + 1] += v.y; nei[j4 + 2] += v.z; nei[j4 + 3] += v.w;
        }
    }
    float acc[8];
#pragma unroll
    for (int dd = 0; dd < 8; dd++) acc[dd] = ldw(Wo_b, t * 32 + d0 + dd, bf);
    for (int kc = 0; kc < 8; kc++) {
        float xv[32];
#pragma unroll
        for (int kk = 0; kk < 32; kk++) xv[kk] = xT[(size_t)(kc * 32 + kk) * NA + a];
#pragma unroll
        for (int dd = 0; dd < 8; dd++) {
            const float* w = &WL[(d0 + dd) * 297 + kc * 32];
#pragma unroll
            for (int kk = 0; kk < 32; kk++) acc[dd] += xv[kk] * w[kk];
        }
    }
    const int wv = threadIdx.x >> 6, l = threadIdx.x & 63, aw = al & 15;
#pragma unroll
    for (int dd = 0; dd < 8; dd++) {
        const float* w = &WL[(d0 + dd) * 297 + 256];
        float s = acc[dd];
#pragma unroll
        for (int j = 0; j < 32; j++) s += nei[j] * w[j];
        s = fmaxf(s, 0.f);
        if (a == 0) s = 0.f;
        tb[wv][aw * 33 + d0 + dd] = s;
    }
    __syncthreads();
    int abase = xb * 64 + wv * 16;
#pragma unroll
    for (int i = 0; i < 8; i++) {
        int idx = i * 64 + l;
        int mm = idx >> 5, d = idx & 31;
        float v = tb[wv][mm * 33 + d];
        size_t dst;
        if (s2 == 0) dst = (size_t)(abase + mm) * 256 + hh * 32 + d;
        else dst = (size_t)s2 * 1048576 + (size_t)hh * 131072 + (size_t)(abase + mm) * 32 + d;
        qkv[dst] = v;
    }
}

// ---------------- per-molecule 32x32 attention block ----------------
// grid (nmol, 4); block 64 (one wave, 2 heads)
__global__ __launch_bounds__(64) void k_attn_mol(
    const float* __restrict__ Qp, const float* __restrict__ Kp, const float* __restrict__ Vp,
    const int* __restrict__ scopes, float* __restrict__ ctx)
{
    int mol = blockIdx.x;
    int g = threadIdx.x >> 5;
    int head = blockIdx.y * 2 + g;
    int lane = threadIdx.x & 31;
    int start = scopes[2 * mol];
    int len = min(scopes[2 * mol + 1], 32);
    if (len <= 0) return;
    __shared__ float Ql[2][32 * 36], Kl[2][32 * 36], Vl[2][32 * 36], Pl[2][32 * 36];
    for (int i = 0; i < len; i++) {
        if (start + i >= NA) break;
        size_t base = (size_t)(start + i) * 256 + head * 32 + lane;
        Ql[g][i * 36 + lane] = Qp[base];
        Kl[g][i * 36 + lane] = Kp[base];
        Vl[g][i * 36 + lane] = Vp[base];
    }
    for (int i = len; i < 32; i++) { Vl[g][i * 36 + lane] = 0.f; Kl[g][i * 36 + lane] = 0.f; }
    float kreg[32];
#pragma unroll
    for (int d2 = 0; d2 < 32; d2++) kreg[d2] = Kl[g][lane * 36 + d2];
    const float scale = 0.17677669529663687f;   // 1/sqrt(32)
    for (int i = 0; i < len; i++) {
        float s = 0.f;
#pragma unroll
        for (int d2 = 0; d2 < 32; d2++) s += Ql[g][i * 36 + d2] * kreg[d2];
        s *= scale;
        if (lane >= len) s = -1e30f;
        float mx = s;
#pragma unroll
        for (int off = 16; off > 0; off >>= 1) mx = fmaxf(mx, __shfl_xor(mx, off, 32));
        float p = __expf(s - mx);
        if (lane >= len) p = 0.f;
        float sum = p;
#pragma unroll
        for (int off = 16; off > 0; off >>= 1) sum += __shfl_xor(sum, off, 32);
        Pl[g][i * 36 + lane] = p / sum;
    }
    for (int i = 0; i < len; i++) {
        if (start + i >= NA) break;
        float acc = 0.f;
#pragma unroll
        for (int j = 0; j < 32; j++) acc += Pl[g][i * 36 + j] * Vl[g][j * 36 + lane];
        ctx[(size_t)(start + i) * 256 + head * 32 + lane] = acc;
    }
}

// ---------------- column sums of Vp (for uniform-softmax rows) ----------------
// grid 32; block 256; partial[b][c] = sum of Vp rows [b*128, b*128+128)
__global__ __launch_bounds__(256) void k_colsum(
    const float* __restrict__ Vp, float* __restrict__ partial)
{
    int b = blockIdx.x, c = threadIdx.x;
    float a0 = 0.f, a1 = 0.f, a2 = 0.f, a3 = 0.f;
    for (int j = 0; j < 32; j++) {
        const float* rp = Vp + ((size_t)b * 128 + j * 4) * 256 + c;
        a0 += rp[0]; a1 += rp[256]; a2 += rp[512]; a3 += rp[768];
    }
    partial[b * 256 + c] = a0 + a1 + a2 + a3;
}

// ---------------- degenerate attention rows: atom 0 -> V[0]; uncovered atoms -> mean(V) ----------------
// grid NA; block 256 (only ~32 blocks do work)
__global__ __launch_bounds__(256) void k_fill(
    const float* __restrict__ Vp, const float* __restrict__ partial,
    const int* __restrict__ molid, float* __restrict__ ctx)
{
    int a = blockIdx.x, c = threadIdx.x;
    if (molid[a] >= 0) return;
    float v;
    if (a == 0) v = Vp[c];
    else {
        float s = 0.f;
#pragma unroll
        for (int b = 0; b < 32; b++) s += partial[b * 256 + c];
        v = s * (1.f / 4096.f);
    }
    ctx[(size_t)a * 256 + c] = v;
}

// ---------------- layernorm -> out (bf16 or f32 per flag) ----------------
__global__ __launch_bounds__(256) void k_ln(
    const float* __restrict__ xo, const void* __restrict__ g_, const void* __restrict__ b_,
    void* __restrict__ out, const int* __restrict__ flag)
{
    int bf = *flag;
    int a = blockIdx.x, c = threadIdx.x;
    float v = xo[(size_t)a * 256 + c];
    __shared__ float red[4], red2[4];
    float s = v;
#pragma unroll
    for (int off = 32; off > 0; off >>= 1) s += __shfl_down(s, off);
    int w = threadIdx.x >> 6, ln2 = threadIdx.x & 63;
    if (ln2 == 0) red[w] = s;
    __syncthreads();
    float mu = (red[0] + red[1] + red[2] + red[3]) * (1.f / 256.f);
    float dv = v - mu;
    float sq = dv * dv;
#pragma unroll
    for (int off = 32; off > 0; off >>= 1) sq += __shfl_down(sq, off);
    if (ln2 == 0) red2[w] = sq;
    __syncthreads();
    float var = (red2[0] + red2[1] + red2[2] + red2[3]) * (1.f / 256.f);
    float y = dv * rsqrtf(var + 1e-5f) * ldw(g_, c, bf) + ldw(b_, c, bf);
    size_t idx = (size_t)a * 256 + c;
    if (bf) ((bf16*)out)[idx] = f2b(y);
    else    ((float*)out)[idx] = y;
}

extern "C" void kernel_launch(void* const* d_in, const int* in_sizes, int n_in,
                              void* d_out, int out_size, void* d_ws, size_t ws_size,
                              hipStream_t stream)
{
    const void* fnode  = d_in[0];
    const void* fmess  = d_in[1];
    const int*  agraph = (const int*)d_in[2];
    const int*  bgraph = (const int*)d_in[3];
    const int*  scopes = (const int*)d_in[4];
    const void* W_i_w  = d_in[5];
    const void* Wz_w   = d_in[6];
    const void* Wz_b   = d_in[7];
    const void* Wr_w   = d_in[8];
    const void* Ur_w   = d_in[9];
    const void* Ur_b   = d_in[10];
    const void* Wh_w   = d_in[11];
    const void* Wh_b   = d_in[12];
    const void* Wo_w   = d_in[13];
    const void* Wo_b   = d_in[14];
    const void* attn_w = d_in[15];
    const void* attn_b = d_in[16];
    const void* aow    = d_in[17];
    const void* bww    = d_in[18];
    const void* ln_g   = d_in[19];
    const void* ln_b   = d_in[20];
    int nmol = in_sizes[4] / 2;

    // -------- workspace layout (floats); tch chosen from ws_size --------
    const size_t fixedF = 1048576 + (size_t)288 * NM + 3 * 1048576 + NA + 1 + 32 * 256;
    int tch = 2;
    if (ws_size / 4 >= fixedF + 5ull * 8 * 32 * NM) tch = 8;        // ~120 MB
    else if (ws_size / 4 >= fixedF + 5ull * 4 * 32 * NM) tch = 4;   // ~78 MB
    const size_t CS = (size_t)tch * 32 * NM;

    float* p   = (float*)d_ws;
    float* xT  = p;                    p += 1048576;
    float* hmT = p;                    p += (size_t)288 * NM;       // 4,718,592
    float* cs  = p;                    p += 5 * CS;
    float* qkv = p;                    p += 3 * 1048576;
    int*   molid = (int*)p;            p += NA;
    int*   dflag = (int*)p;            p += 1;
    float* partial = p;                p += 32 * 256;

    float* r1 = cs;
    float* az = cs + CS;
    float* ah = cs + 2 * CS;
    float* h0 = cs + 3 * CS;
    float* h1 = cs + 4 * CS;
    // phase-A temporaries nested inside qkv (dead before qkv is written):
    float* fnode_f = qkv;              // 401,408
    float* x       = qkv + 524288;     // 1,048,576
    // post-loop aliases:
    float* Qp  = cs;                   // 1,048,576 each
    float* Kp  = cs + 1048576;
    float* Vp  = cs + 2097152;
    float* ctx = hmT;
    float* y1  = hmT + 1048576;
    float* xo  = hmT + 2097152;

    k_flag<<<1, 64, 0, stream>>>(fnode, dflag);
    k_cast<<<(401408 + 255) / 256, 256, 0, stream>>>(fnode, fnode_f, 401408, dflag);
    k_gemm_nt<<<256, 256, 0, stream>>>(fnode_f, W_i_w, 0, nullptr, 0, 0, x, 98, dflag);
    k_xpose<<<dim3(128, 8), 256, 0, stream>>>(x, xT);
    k_hmess_t<<<dim3(NM / 32, 9), 256, 0, stream>>>(x, fmess, hmT, dflag);
    k_molmap<<<(NA + 255) / 256, 256, 0, stream>>>(scopes, nmol, molid);

    for (int tc = 0; tc < 24 / tch; tc++) {
        int t0 = tc * tch;
        k_pre<<<dim3(NM / 512, tch, 4), 256, 0, stream>>>(
            hmT, Wr_w, Wz_w, Wh_w, Ur_b, Wz_b, Wh_b, t0, r1, az, ah, dflag);
        k_step0<<<dim3(NM / 64, tch), 256, 0, stream>>>(az, ah, h1);
        k_step<<<256 * tch, 256, 0, stream>>>(h1, h0, r1, az, ah, bgraph, Ur_w, Wz_w, Wh_w, t0, tch, dflag);
        k_step<<<256 * tch, 256, 0, stream>>>(h0, h1, r1, az, ah, bgraph, Ur_w, Wz_w, Wh_w, t0, tch, dflag);
        k_outs<<<64 * tch, 256, 0, stream>>>(xT, h1, agraph, Wo_w, Wo_b, t0, tch, qkv, dflag);
    }

    // projections (qkv planes already in queries/keys/values layout); offsets in ELEMENTS
    k_gemm_nt<<<256, 256, 0, stream>>>(qkv,           attn_w, 0,      attn_b, 0,   1, Qp, 256, dflag);
    k_gemm_nt<<<256, 256, 0, stream>>>(qkv + 1048576, attn_w, 65536,  attn_b, 256, 1, Kp, 256, dflag);
    k_gemm_nt<<<256, 256, 0, stream>>>(qkv + 2097152, attn_w, 131072, attn_b, 512, 1, Vp, 256, dflag);

    k_attn_mol<<<dim3(nmol, 4), 64, 0, stream>>>(Qp, Kp, Vp, scopes, ctx);
    k_colsum<<<32, 256, 0, stream>>>(Vp, partial);
    k_fill<<<NA, 256, 0, stream>>>(Vp, partial, molid, ctx);

    k_gemm_nt<<<256, 256, 0, stream>>>(ctx, aow, 0, nullptr, 0, 0, y1, 256, dflag);
    k_gemm_nt<<<256, 256, 0, stream>>>(y1,  bww, 0, nullptr, 0, 0, xo, 256, dflag);
    k_ln<<<NA, 256, 0, stream>>>(xo, ln_g, ln_b, d_out, dflag);
    (void)ws_size; (void)out_size; (void)n_in;
}

// Round 5
// 2337.975 us; speedup vs baseline: 1.5684x; 1.5684x over previous
//
#include <hip/hip_runtime.h>
#include <hip/hip_bf16.h>

typedef __hip_bfloat16 bf16;
typedef __attribute__((ext_vector_type(8))) short bh8;     // 8 bf16 (4 VGPRs)
typedef __attribute__((ext_vector_type(4))) float f32x4;

#define NA    4096
#define NM    16384
#define WLD   296    // LDS row stride (u16) for staged weights: 16B-aligned, conflict-free

__device__ __forceinline__ float b2f(bf16 v) { return __bfloat162float(v); }

__device__ __forceinline__ float ldw(const void* p, size_t i, int bf) {
    if (bf) return b2f(((const bf16*)p)[i]);
    return ((const float*)p)[i];
}

__device__ __forceinline__ unsigned short f2b_bits(float f) {
    union { unsigned u; float ff; } cv; cv.ff = f;
    return (unsigned short)((cv.u + 0x7FFFu + ((cv.u >> 16) & 1u)) >> 16);
}

__device__ __forceinline__ bf16 f2b(float f) {
    unsigned short us = f2b_bits(f);
    bf16 out; __builtin_memcpy(&out, &us, 2);
    return out;
}

// ---------------- dtype probe: bf16 vs f32 float buffers ----------------
__global__ void k_flag(const void* __restrict__ fnode, int* __restrict__ flag) {
    if (threadIdx.x == 0 && blockIdx.x == 0) {
        const unsigned short* u = (const unsigned short*)fnode;
        int cnt = 0;
        for (int i = 0; i < 64; i++) {
            unsigned short us = u[2 * i];
            unsigned ex = (us >> 7) & 0xFF;
            if (us == 0 || (ex >= 105 && ex <= 134)) cnt++;
        }
        *flag = (cnt >= 48) ? 1 : 0;
    }
}

// ---------------- cast fnode -> f32 ----------------
__global__ void k_cast(const void* __restrict__ in, float* __restrict__ out, int n,
                       const int* __restrict__ flag) {
    int bf = *flag;
    int i = blockIdx.x * 256 + threadIdx.x;
    if (i < n) out[i] = ldw(in, i, bf);
}

// ---------------- GEMM: C[4096 x 256] = A[4096 x K] * W[256 x K]^T (+bias) ----------------
__global__ __launch_bounds__(256) void k_gemm_nt(
    const float* __restrict__ A, const void* __restrict__ W, size_t woff,
    const void* __restrict__ bias, size_t boff, int has_bias,
    float* __restrict__ C, int K, const int* __restrict__ flag)
{
    int bf = *flag;
    __shared__ float Wl[256 * 33];
    __shared__ float Al[32 * 20];
    int a0 = blockIdx.x * 16;
    int c  = threadIdx.x;
    float acc[16];
#pragma unroll
    for (int i = 0; i < 16; i++) acc[i] = 0.f;

    for (int k0 = 0; k0 < K; k0 += 32) {
        __syncthreads();
        for (int i = threadIdx.x; i < 256 * 32; i += 256) {
            int c2 = i >> 5, kk = i & 31, k = k0 + kk;
            Wl[c2 * 33 + kk] = (k < K) ? ldw(W, woff + (size_t)c2 * K + k, bf) : 0.f;
        }
        for (int i = threadIdx.x; i < 512; i += 256) {
            int aa = i >> 5, kk = i & 31, k = k0 + kk;
            Al[kk * 20 + aa] = (k < K) ? A[(size_t)(a0 + aa) * K + k] : 0.f;
        }
        __syncthreads();
#pragma unroll
        for (int kk = 0; kk < 32; kk++) {
            float w = Wl[c * 33 + kk];
            const float4* ap = (const float4*)&Al[kk * 20];
            float4 a01 = ap[0], a23 = ap[1], a45 = ap[2], a67 = ap[3];
            acc[0]  += a01.x * w; acc[1]  += a01.y * w; acc[2]  += a01.z * w; acc[3]  += a01.w * w;
            acc[4]  += a23.x * w; acc[5]  += a23.y * w; acc[6]  += a23.z * w; acc[7]  += a23.w * w;
            acc[8]  += a45.x * w; acc[9]  += a45.y * w; acc[10] += a45.z * w; acc[11] += a45.w * w;
            acc[12] += a67.x * w; acc[13] += a67.y * w; acc[14] += a67.z * w; acc[15] += a67.w * w;
        }
    }
    float bv = has_bias ? ldw(bias, boff + c, bf) : 0.f;
#pragma unroll
    for (int i = 0; i < 16; i++) C[(size_t)(a0 + i) * 256 + c] = acc[i] + bv;
}

// ---------------- transpose x (4096x256) -> xT (256x4096) ----------------
__global__ __launch_bounds__(256) void k_xpose(const float* __restrict__ x, float* __restrict__ xT) {
    __shared__ float tl[32][33];
    int bx = blockIdx.x, by = blockIdx.y;
    int tx = threadIdx.x & 31, ty = threadIdx.x >> 5;
#pragma unroll
    for (int i = 0; i < 4; i++)
        tl[ty + i * 8][tx] = x[(size_t)(bx * 32 + ty + i * 8) * 256 + by * 32 + tx];
    __syncthreads();
#pragma unroll
    for (int i = 0; i < 4; i++)
        xT[(size_t)(by * 32 + ty + i * 8) * NA + bx * 32 + tx] = tl[tx][ty + i * 8];
}

// ---------------- build bf16 k-tiled hmess: hmB[kb][m][8], kb<36 (262 valid k, zero-pad) ----------------
// grid (NM/32, 9); block 256.
__global__ __launch_bounds__(256) void k_hmess_b(
    const float* __restrict__ x, const void* __restrict__ fmess,
    unsigned short* __restrict__ hmB, const int* __restrict__ flag)
{
    int bf = *flag;
    const int mb = blockIdx.x * 32;
    const int kc = blockIdx.y;     // 0..8
    const int k0 = kc * 32;
    __shared__ float tl[32][33];
    __shared__ int srcs[32];
    const int tid = threadIdx.x;
    if (tid < 32) {
        int s = (int)ldw(fmess, (size_t)(mb + tid) * 8, bf);
        srcs[tid] = min(max(s, 0), NA - 1);
    }
    __syncthreads();
    {
        const int ml = tid >> 3, kg = (tid & 7) * 4;
        if (kc < 8) {
            const float4 v = *(const float4*)&x[(size_t)srcs[ml] * 256 + k0 + kg];
            tl[ml][kg] = v.x; tl[ml][kg + 1] = v.y; tl[ml][kg + 2] = v.z; tl[ml][kg + 3] = v.w;
        } else {
#pragma unroll
            for (int j = 0; j < 4; j++) {
                int k = k0 + kg + j;
                float v = (k < 262) ? ldw(fmess, (size_t)(mb + ml) * 8 + 2 + (k - 256), bf) : 0.f;
                tl[ml][kg + j] = v;
            }
        }
    }
    __syncthreads();
    {
        const int kl = tid >> 3;             // local k 0..31
        const int mg = (tid & 7) * 4;        // 4 m's
        const int kb = kc * 4 + (kl >> 3);
        const int j  = kl & 7;
#pragma unroll
        for (int i = 0; i < 4; i++)
            hmB[((size_t)kb * NM + mb + mg + i) * 8 + j] = f2b_bits(tl[mg + i][kl]);
    }
}

// ---------------- mol membership map ----------------
__global__ void k_molmap(const int* __restrict__ scopes, int nmol, int* __restrict__ molid) {
    int a = blockIdx.x * 256 + threadIdx.x;
    if (a >= NA) return;
    int mid = -1;
    for (int s2 = 0; s2 < nmol; s2++) {
        int st = scopes[2 * s2], ln = scopes[2 * s2 + 1];
        if (a >= st && a < st + ln) mid = s2;
    }
    molid[a] = mid;
}

// ---------------- MFMA precompute of r1/az/ah ----------------
// grid (NM/128, tch); block 256 = 4 waves; wave computes 32d x 32m for all 3 mats.
// Output layout [(ti*32+d)*NM + m].
__global__ __launch_bounds__(256) void k_pre_mfma(
    const unsigned short* __restrict__ hmB,
    const void* __restrict__ Wr_w, const void* __restrict__ Wz_w, const void* __restrict__ Wh_w,
    const void* __restrict__ Ur_b, const void* __restrict__ Wz_b, const void* __restrict__ Wh_b,
    int t0, float* __restrict__ r1, float* __restrict__ az, float* __restrict__ ah,
    const int* __restrict__ flag)
{
    int bf = *flag;
    const int ti = blockIdx.y, t = t0 + ti;
    __shared__ unsigned short WL[3 * 32 * WLD];
    __shared__ float BL[3 * 32];
    for (int i = threadIdx.x; i < 3 * 32 * WLD; i += 256) {
        int mt = i / (32 * WLD);
        int rr = i - mt * (32 * WLD);
        int d = rr / WLD, k = rr - d * WLD;
        unsigned short v = 0;
        if (k < 262) {
            size_t idx;
            const void* W;
            if (mt == 0)      { W = Wr_w; idx = ((size_t)t * 32 + d) * 262 + k; }
            else if (mt == 1) { W = Wz_w; idx = ((size_t)t * 32 + d) * 294 + k; }
            else              { W = Wh_w; idx = ((size_t)t * 32 + d) * 294 + k; }
            if (bf) v = ((const unsigned short*)W)[idx];
            else    v = f2b_bits(((const float*)W)[idx]);
        }
        WL[i] = v;
    }
    if (threadIdx.x < 96) {
        int mt = threadIdx.x >> 5, d = threadIdx.x & 31;
        const void* B = (mt == 0) ? Ur_b : (mt == 1) ? Wz_b : Wh_b;
        BL[threadIdx.x] = ldw(B, t * 32 + d, bf);
    }
    __syncthreads();
    const int w = threadIdx.x >> 6, lane = threadIdx.x & 63;
    const int col = lane & 15, g = lane >> 4;
    const int m0 = blockIdx.x * 128 + w * 32;

    f32x4 acc[3][2][2];
#pragma unroll
    for (int mt = 0; mt < 3; mt++)
#pragma unroll
        for (int dt = 0; dt < 2; dt++)
#pragma unroll
            for (int nt = 0; nt < 2; nt++) {
                acc[mt][dt][nt][0] = 0.f; acc[mt][dt][nt][1] = 0.f;
                acc[mt][dt][nt][2] = 0.f; acc[mt][dt][nt][3] = 0.f;
            }

    for (int ks = 0; ks < 9; ks++) {
        const int kb = ks * 4 + g;
        bh8 bfrag[2];
#pragma unroll
        for (int nt = 0; nt < 2; nt++)
            bfrag[nt] = *(const bh8*)&hmB[((size_t)kb * NM + m0 + nt * 16 + col) * 8];
        bh8 afrag[3][2];
#pragma unroll
        for (int mt = 0; mt < 3; mt++)
#pragma unroll
            for (int dt = 0; dt < 2; dt++)
                afrag[mt][dt] = *(const bh8*)&WL[mt * 32 * WLD + (dt * 16 + col) * WLD + ks * 32 + g * 8];
#pragma unroll
        for (int mt = 0; mt < 3; mt++)
#pragma unroll
            for (int dt = 0; dt < 2; dt++)
#pragma unroll
            for (int nt = 0; nt < 2; nt++)
                acc[mt][dt][nt] = __builtin_amdgcn_mfma_f32_16x16x32_bf16(
                    afrag[mt][dt], bfrag[nt], acc[mt][dt][nt], 0, 0, 0);
    }
#pragma unroll
    for (int mt = 0; mt < 3; mt++) {
        float* out = (mt == 0) ? r1 : (mt == 1) ? az : ah;
#pragma unroll
        for (int dt = 0; dt < 2; dt++)
#pragma unroll
            for (int r = 0; r < 4; r++) {
                int d = dt * 16 + g * 4 + r;
                float b = BL[mt * 32 + d];
#pragma unroll
                for (int nt = 0; nt < 2; nt++)
                    out[(size_t)(ti * 32 + d) * NM + m0 + nt * 16 + col] = acc[mt][dt][nt][r] + b;
            }
    }
}

// ---------------- depth-1 GRU step (h_in == 0): h = sigmoid(az)*tanh(ah)*mask ----------------
// grid (NM/64, tch); block 256 = 64 messages x 4 d-quarters
__global__ __launch_bounds__(256) void k_step0(
    const float* __restrict__ az, const float* __restrict__ ah, float* __restrict__ h_out)
{
    const int ti = blockIdx.y;
    __shared__ float tb[4][16 * 33];
    const int q = threadIdx.x & 3, ml = threadIdx.x >> 2;
    const int m = blockIdx.x * 64 + ml;
    const int d0 = q * 8;
    const int wv = threadIdx.x >> 6, l = threadIdx.x & 63, mw = ml & 15;
    float msk_m = (m == 0) ? 0.f : 1.f;
#pragma unroll
    for (int dd = 0; dd < 8; dd++) {
        int d = d0 + dd;
        float zacc = az[(size_t)(ti * 32 + d) * NM + m];
        float pacc = ah[(size_t)(ti * 32 + d) * NM + m];
        float zz = 1.f / (1.f + __expf(-zacc));
        float cl = fminf(fmaxf(pacc, -20.f), 20.f);
        float e2 = __expf(2.f * cl);
        float th = (e2 - 1.f) / (e2 + 1.f);
        tb[wv][mw * 33 + d] = zz * th * msk_m;
    }
    __syncthreads();
    float* ho = h_out + (size_t)ti * NM * 32 + ((size_t)blockIdx.x * 64 + wv * 16) * 32;
#pragma unroll
    for (int i = 0; i < 8; i++) {
        int idx = i * 64 + l;
        int mm = idx >> 5, d = idx & 31;
        ho[idx] = tb[wv][mm * 33 + d];
    }
}

// ---------------- full GRU depth step (2-D grid, natural order) ----------------
// grid (NM/64, tch); block 256 = 64 messages x 4 d-quarters; h layout [(ti*NM+m)*32+d]
__global__ __launch_bounds__(256, 4) void k_step(
    const float* __restrict__ h_in, float* __restrict__ h_out,
    const float* __restrict__ r1, const float* __restrict__ az, const float* __restrict__ ah,
    const int* __restrict__ bgraph,
    const void* __restrict__ Ur_w, const void* __restrict__ Wz_w, const void* __restrict__ Wh_w,
    int t0, const int* __restrict__ flag)
{
    int bf = *flag;
    const int ti = blockIdx.y, t = t0 + ti;
    __shared__ float UrL[32 * 37], WzL[32 * 37], WhL[32 * 37];
    __shared__ float tb[4][16 * 33];
    for (int i = threadIdx.x; i < 32 * 37; i += 256) {
        int d = i / 37, j = i - d * 37;
        float u = 0.f, wz = 0.f, wh = 0.f;
        if (j < 32) {
            u  = ldw(Ur_w, ((size_t)t * 32 + d) * 32 + j, bf);
            wz = ldw(Wz_w, ((size_t)t * 32 + d) * 294 + 262 + j, bf);
            wh = ldw(Wh_w, ((size_t)t * 32 + d) * 294 + 262 + j, bf);
        }
        UrL[i] = u; WzL[i] = wz; WhL[i] = wh;
    }
    __syncthreads();
    const int q  = threadIdx.x & 3;
    const int ml = threadIdx.x >> 2;
    const int m  = blockIdx.x * 64 + ml;
    const int d0 = q * 8;
    const float* hb = h_in + (size_t)ti * NM * 32;

    float r1v[8];
#pragma unroll
    for (int dd = 0; dd < 8; dd++)
        r1v[dd] = r1[(size_t)(ti * 32 + d0 + dd) * NM + m];

    float sumh[8], rh[8];
#pragma unroll
    for (int dd = 0; dd < 8; dd++) { sumh[dd] = 0.f; rh[dd] = 0.f; }

#pragma unroll
    for (int nb = 0; nb < 6; nb++) {
        int bg = bgraph[m * 6 + nb];
        bg = min(max(bg, 0), NM - 1);
        const float* hr = hb + (size_t)bg * 32;
        float hc[32];
#pragma unroll
        for (int j4 = 0; j4 < 32; j4 += 4) {
            float4 v = *(const float4*)&hr[j4];
            hc[j4] = v.x; hc[j4 + 1] = v.y; hc[j4 + 2] = v.z; hc[j4 + 3] = v.w;
        }
        float4 o1 = *(const float4*)&hr[d0];
        float4 o2 = *(const float4*)&hr[d0 + 4];
        float hown[8] = {o1.x, o1.y, o1.z, o1.w, o2.x, o2.y, o2.z, o2.w};
#pragma unroll
        for (int dd = 0; dd < 8; dd++) {
            float acc = r1v[dd];
            const float* ur = &UrL[(d0 + dd) * 37];
#pragma unroll
            for (int j = 0; j < 32; j++) acc += hc[j] * ur[j];
            float rr = 1.f / (1.f + __expf(-acc));
            sumh[dd] += hown[dd];
            rh[dd] += rr * hown[dd];
        }
    }
    float recvS[4][8], recvH[4][8];
#pragma unroll
    for (int e = 0; e < 4; e++)
#pragma unroll
        for (int jj = 0; jj < 8; jj++) {
            recvS[e][jj] = __shfl_xor(sumh[jj], e, 4);
            recvH[e][jj] = __shfl_xor(rh[jj], e, 4);
        }
    float msk_m = (m == 0) ? 0.f : 1.f;
    const int wv = threadIdx.x >> 6, l = threadIdx.x & 63, mw = ml & 15;
#pragma unroll
    for (int dd = 0; dd < 8; dd++) {
        int d = d0 + dd;
        float zacc = az[(size_t)(ti * 32 + d) * NM + m];
        float pacc = ah[(size_t)(ti * 32 + d) * NM + m];
#pragma unroll
        for (int e = 0; e < 4; e++) {
            int jb = (q ^ e) * 8;
            const float* wz = &WzL[d * 37 + jb];
            const float* wh = &WhL[d * 37 + jb];
#pragma unroll
            for (int jj = 0; jj < 8; jj++) {
                zacc += recvS[e][jj] * wz[jj];
                pacc += recvH[e][jj] * wh[jj];
            }
        }
        float zz = 1.f / (1.f + __expf(-zacc));
        float cl = fminf(fmaxf(pacc, -20.f), 20.f);
        float e2 = __expf(2.f * cl);
        float th = (e2 - 1.f) / (e2 + 1.f);
        tb[wv][mw * 33 + d] = ((1.f - zz) * sumh[dd] + zz * th) * msk_m;
    }
    __syncthreads();
    float* ho = h_out + (size_t)ti * NM * 32 + ((size_t)blockIdx.x * 64 + wv * 16) * 32;
#pragma unroll
    for (int i = 0; i < 8; i++) {
        int idx = i * 64 + l;
        int mm = idx >> 5, d = idx & 31;
        ho[idx] = tb[wv][mm * 33 + d];
    }
}

// ---------------- outs = relu([x, nei] @ Wo^T + b) * node_mask, scattered into qkv ----------------
// grid (NA/64, tch); block 256 = 64 atoms x 4 d-quarters
__global__ __launch_bounds__(256) void k_outs(
    const float* __restrict__ xT, const float* __restrict__ h,
    const int* __restrict__ agraph, const void* __restrict__ Wo_w, const void* __restrict__ Wo_b,
    int t0, float* __restrict__ qkv, const int* __restrict__ flag)
{
    int bf = *flag;
    const int ti = blockIdx.y, t = t0 + ti;
    const int hh = t / 3, s2 = t - 3 * hh;
    __shared__ float WL[32 * 297];
    __shared__ float tb[4][16 * 33];
    for (int i = threadIdx.x; i < 32 * 297; i += 256) {
        int d = i / 297, k = i - d * 297;
        WL[i] = (k < 288) ? ldw(Wo_w, ((size_t)t * 32 + d) * 288 + k, bf) : 0.f;
    }
    __syncthreads();
    const int q = threadIdx.x & 3, al = threadIdx.x >> 2;
    const int a = blockIdx.x * 64 + al;
    const int d0 = q * 8;
    float nei[32];
#pragma unroll
    for (int j = 0; j < 32; j++) nei[j] = 0.f;
#pragma unroll
    for (int nb = 0; nb < 6; nb++) {
        int ag = agraph[a * 6 + nb];
        ag = min(max(ag, 0), NM - 1);
        const float* hr = h + ((size_t)ti * NM + ag) * 32;
#pragma unroll
        for (int j4 = 0; j4 < 32; j4 += 4) {
            float4 v = *(const float4*)&hr[j4];
            nei[j4] += v.x; nei[j4 + 1] += v.y; nei[j4 + 2] += v.z; nei[j4 + 3] += v.w;
        }
    }
    float acc[8];
#pragma unroll
    for (int dd = 0; dd < 8; dd++) acc[dd] = ldw(Wo_b, t * 32 + d0 + dd, bf);
    for (int kc = 0; kc < 8; kc++) {
        float xv[32];
#pragma unroll
        for (int kk = 0; kk < 32; kk++) xv[kk] = xT[(size_t)(kc * 32 + kk) * NA + a];
#pragma unroll
        for (int dd = 0; dd < 8; dd++) {
            const float* w = &WL[(d0 + dd) * 297 + kc * 32];
#pragma unroll
            for (int kk = 0; kk < 32; kk++) acc[dd] += xv[kk] * w[kk];
        }
    }
    const int wv = threadIdx.x >> 6, l = threadIdx.x & 63, aw = al & 15;
#pragma unroll
    for (int dd = 0; dd < 8; dd++) {
        const float* w = &WL[(d0 + dd) * 297 + 256];
        float s = acc[dd];
#pragma unroll
        for (int j = 0; j < 32; j++) s += nei[j] * w[j];
        s = fmaxf(s, 0.f);
        if (a == 0) s = 0.f;
        tb[wv][aw * 33 + d0 + dd] = s;
    }
    __syncthreads();
    int abase = blockIdx.x * 64 + wv * 16;
#pragma unroll
    for (int i = 0; i < 8; i++) {
        int idx = i * 64 + l;
        int mm = idx >> 5, d = idx & 31;
        float v = tb[wv][mm * 33 + d];
        size_t dst;
        if (s2 == 0) dst = (size_t)(abase + mm) * 256 + hh * 32 + d;
        else dst = (size_t)s2 * 1048576 + (size_t)hh * 131072 + (size_t)(abase + mm) * 32 + d;
        qkv[dst] = v;
    }
}

// ---------------- per-molecule 32x32 attention block ----------------
__global__ __launch_bounds__(64) void k_attn_mol(
    const float* __restrict__ Qp, const float* __restrict__ Kp, const float* __restrict__ Vp,
    const int* __restrict__ scopes, float* __restrict__ ctx)
{
    int mol = blockIdx.x;
    int g = threadIdx.x >> 5;
    int head = blockIdx.y * 2 + g;
    int lane = threadIdx.x & 31;
    int start = scopes[2 * mol];
    int len = min(scopes[2 * mol + 1], 32);
    if (len <= 0) return;
    __shared__ float Ql[2][32 * 36], Kl[2][32 * 36], Vl[2][32 * 36], Pl[2][32 * 36];
    for (int i = 0; i < len; i++) {
        if (start + i >= NA) break;
        size_t base = (size_t)(start + i) * 256 + head * 32 + lane;
        Ql[g][i * 36 + lane] = Qp[base];
        Kl[g][i * 36 + lane] = Kp[base];
        Vl[g][i * 36 + lane] = Vp[base];
    }
    for (int i = len; i < 32; i++) { Vl[g][i * 36 + lane] = 0.f; Kl[g][i * 36 + lane] = 0.f; }
    float kreg[32];
#pragma unroll
    for (int d2 = 0; d2 < 32; d2++) kreg[d2] = Kl[g][lane * 36 + d2];
    const float scale = 0.17677669529663687f;   // 1/sqrt(32)
    for (int i = 0; i < len; i++) {
        float s = 0.f;
#pragma unroll
        for (int d2 = 0; d2 < 32; d2++) s += Ql[g][i * 36 + d2] * kreg[d2];
        s *= scale;
        if (lane >= len) s = -1e30f;
        float mx = s;
#pragma unroll
        for (int off = 16; off > 0; off >>= 1) mx = fmaxf(mx, __shfl_xor(mx, off, 32));
        float p = __expf(s - mx);
        if (lane >= len) p = 0.f;
        float sum = p;
#pragma unroll
        for (int off = 16; off > 0; off >>= 1) sum += __shfl_xor(sum, off, 32);
        Pl[g][i * 36 + lane] = p / sum;
    }
    for (int i = 0; i < len; i++) {
        if (start + i >= NA) break;
        float acc = 0.f;
#pragma unroll
        for (int j = 0; j < 32; j++) acc += Pl[g][i * 36 + j] * Vl[g][j * 36 + lane];
        ctx[(size_t)(start + i) * 256 + head * 32 + lane] = acc;
    }
}

// ---------------- column sums of Vp (for uniform-softmax rows) ----------------
__global__ __launch_bounds__(256) void k_colsum(
    const float* __restrict__ Vp, float* __restrict__ partial)
{
    int b = blockIdx.x, c = threadIdx.x;
    float a0 = 0.f, a1 = 0.f, a2 = 0.f, a3 = 0.f;
    for (int j = 0; j < 32; j++) {
        const float* rp = Vp + ((size_t)b * 128 + j * 4) * 256 + c;
        a0 += rp[0]; a1 += rp[256]; a2 += rp[512]; a3 += rp[768];
    }
    partial[b * 256 + c] = a0 + a1 + a2 + a3;
}

// ---------------- degenerate attention rows ----------------
__global__ __launch_bounds__(256) void k_fill(
    const float* __restrict__ Vp, const float* __restrict__ partial,
    const int* __restrict__ molid, float* __restrict__ ctx)
{
    int a = blockIdx.x, c = threadIdx.x;
    if (molid[a] >= 0) return;
    float v;
    if (a == 0) v = Vp[c];
    else {
        float s = 0.f;
#pragma unroll
        for (int b = 0; b < 32; b++) s += partial[b * 256 + c];
        v = s * (1.f / 4096.f);
    }
    ctx[(size_t)a * 256 + c] = v;
}

// ---------------- layernorm -> out ----------------
__global__ __launch_bounds__(256) void k_ln(
    const float* __restrict__ xo, const void* __restrict__ g_, const void* __restrict__ b_,
    void* __restrict__ out, const int* __restrict__ flag)
{
    int bf = *flag;
    int a = blockIdx.x, c = threadIdx.x;
    float v = xo[(size_t)a * 256 + c];
    __shared__ float red[4], red2[4];
    float s = v;
#pragma unroll
    for (int off = 32; off > 0; off >>= 1) s += __shfl_down(s, off);
    int w = threadIdx.x >> 6, ln2 = threadIdx.x & 63;
    if (ln2 == 0) red[w] = s;
    __syncthreads();
    float mu = (red[0] + red[1] + red[2] + red[3]) * (1.f / 256.f);
    float dv = v - mu;
    float sq = dv * dv;
#pragma unroll
    for (int off = 32; off > 0; off >>= 1) sq += __shfl_down(sq, off);
    if (ln2 == 0) red2[w] = sq;
    __syncthreads();
    float var = (red2[0] + red2[1] + red2[2] + red2[3]) * (1.f / 256.f);
    float y = dv * rsqrtf(var + 1e-5f) * ldw(g_, c, bf) + ldw(b_, c, bf);
    size_t idx = (size_t)a * 256 + c;
    if (bf) ((bf16*)out)[idx] = f2b(y);
    else    ((float*)out)[idx] = y;
}

extern "C" void kernel_launch(void* const* d_in, const int* in_sizes, int n_in,
                              void* d_out, int out_size, void* d_ws, size_t ws_size,
                              hipStream_t stream)
{
    const void* fnode  = d_in[0];
    const void* fmess  = d_in[1];
    const int*  agraph = (const int*)d_in[2];
    const int*  bgraph = (const int*)d_in[3];
    const int*  scopes = (const int*)d_in[4];
    const void* W_i_w  = d_in[5];
    const void* Wz_w   = d_in[6];
    const void* Wz_b   = d_in[7];
    const void* Wr_w   = d_in[8];
    const void* Ur_w   = d_in[9];
    const void* Ur_b   = d_in[10];
    const void* Wh_w   = d_in[11];
    const void* Wh_b   = d_in[12];
    const void* Wo_w   = d_in[13];
    const void* Wo_b   = d_in[14];
    const void* attn_w = d_in[15];
    const void* attn_b = d_in[16];
    const void* aow    = d_in[17];
    const void* bww    = d_in[18];
    const void* ln_g   = d_in[19];
    const void* ln_b   = d_in[20];
    int nmol = in_sizes[4] / 2;

    // -------- workspace layout (f32 units); tch chosen from ws_size --------
    // regA holds hmB (bf16, 36*NM*8 u16 = 2,359,296 f32-equiv) early, ctx/y1/xo (3M f32) late.
    const size_t REGA = 3145728;
    const size_t fixedF = 1048576 + REGA + 3 * 1048576 + NA + 1 + 32 * 256;
    int tch = 2;
    if (ws_size / 4 >= fixedF + 5ull * 8 * 32 * NM + 1024) tch = 8;
    else if (ws_size / 4 >= fixedF + 5ull * 4 * 32 * NM + 1024) tch = 4;
    const size_t CS = (size_t)tch * 32 * NM;

    float* p   = (float*)d_ws;
    float* xT  = p;                    p += 1048576;
    float* regA = p;                   p += REGA;
    float* cs  = p;                    p += 5 * CS;
    float* qkv = p;                    p += 3 * 1048576;
    int*   molid = (int*)p;            p += NA;
    int*   dflag = (int*)p;            p += 1;
    float* partial = p;                p += 32 * 256;

    unsigned short* hmB = (unsigned short*)regA;
    float* ctx = regA;
    float* y1  = regA + 1048576;
    float* xo  = regA + 2097152;

    float* r1 = cs;
    float* az = cs + CS;
    float* ah = cs + 2 * CS;
    float* h0 = cs + 3 * CS;
    float* h1 = cs + 4 * CS;
    // phase-A temporaries nested inside qkv (dead before qkv is written):
    float* fnode_f = qkv;              // 401,408
    float* x       = qkv + 524288;     // 1,048,576
    // post-loop aliases:
    float* Qp  = cs;
    float* Kp  = cs + 1048576;
    float* Vp  = cs + 2097152;

    k_flag<<<1, 64, 0, stream>>>(fnode, dflag);
    k_cast<<<(401408 + 255) / 256, 256, 0, stream>>>(fnode, fnode_f, 401408, dflag);
    k_gemm_nt<<<256, 256, 0, stream>>>(fnode_f, W_i_w, 0, nullptr, 0, 0, x, 98, dflag);
    k_xpose<<<dim3(128, 8), 256, 0, stream>>>(x, xT);
    k_hmess_b<<<dim3(NM / 32, 9), 256, 0, stream>>>(x, fmess, hmB, dflag);
    k_molmap<<<(NA + 255) / 256, 256, 0, stream>>>(scopes, nmol, molid);

    for (int tc = 0; tc < 24 / tch; tc++) {
        int t0 = tc * tch;
        k_pre_mfma<<<dim3(NM / 128, tch), 256, 0, stream>>>(
            hmB, Wr_w, Wz_w, Wh_w, Ur_b, Wz_b, Wh_b, t0, r1, az, ah, dflag);
        k_step0<<<dim3(NM / 64, tch), 256, 0, stream>>>(az, ah, h1);
        k_step<<<dim3(NM / 64, tch), 256, 0, stream>>>(h1, h0, r1, az, ah, bgraph, Ur_w, Wz_w, Wh_w, t0, dflag);
        k_step<<<dim3(NM / 64, tch), 256, 0, stream>>>(h0, h1, r1, az, ah, bgraph, Ur_w, Wz_w, Wh_w, t0, dflag);
        k_outs<<<dim3(NA / 64, tch), 256, 0, stream>>>(xT, h1, agraph, Wo_w, Wo_b, t0, qkv, dflag);
    }

    // projections (qkv planes already in queries/keys/values layout); offsets in ELEMENTS
    k_gemm_nt<<<256, 256, 0, stream>>>(qkv,           attn_w, 0,      attn_b, 0,   1, Qp, 256, dflag);
    k_gemm_nt<<<256, 256, 0, stream>>>(qkv + 1048576, attn_w, 65536,  attn_b, 256, 1, Kp, 256, dflag);
    k_gemm_nt<<<256, 256, 0, stream>>>(qkv + 2097152, attn_w, 131072, attn_b, 512, 1, Vp, 256, dflag);

    k_attn_mol<<<dim3(nmol, 4), 64, 0, stream>>>(Qp, Kp, Vp, scopes, ctx);
    k_colsum<<<32, 256, 0, stream>>>(Vp, partial);
    k_fill<<<NA, 256, 0, stream>>>(Vp, partial, molid, ctx);

    k_gemm_nt<<<256, 256, 0, stream>>>(ctx, aow, 0, nullptr, 0, 0, y1, 256, dflag);
    k_gemm_nt<<<256, 256, 0, stream>>>(y1,  bww, 0, nullptr, 0, 0, xo, 256, dflag);
    k_ln<<<NA, 256, 0, stream>>>(xo, ln_g, ln_b, d_out, dflag);
    (void)ws_size; (void)out_size; (void)n_in;
}

// Round 6
// 1367.245 us; speedup vs baseline: 2.6820x; 1.7100x over previous
//
#include <hip/hip_runtime.h>
#include <hip/hip_bf16.h>

typedef __hip_bfloat16 bf16;
typedef __attribute__((ext_vector_type(8))) short bh8;             // 8 bf16 (4 VGPRs)
typedef __attribute__((ext_vector_type(4))) float f32x4;
typedef __attribute__((ext_vector_type(8))) unsigned short us8;
typedef __attribute__((ext_vector_type(4))) unsigned short us4;

#define NA    4096
#define NM    16384
#define WLD   296    // LDS row stride (u16) for k_pre staged weights

__device__ __forceinline__ float b2f(bf16 v) { return __bfloat162float(v); }

__device__ __forceinline__ float bb(unsigned short u) {
    union { unsigned u; float f; } c; c.u = ((unsigned)u) << 16; return c.f;
}

__device__ __forceinline__ float ldw(const void* p, size_t i, int bf) {
    if (bf) return b2f(((const bf16*)p)[i]);
    return ((const float*)p)[i];
}

__device__ __forceinline__ unsigned short f2b_bits(float f) {
    union { unsigned u; float ff; } cv; cv.ff = f;
    return (unsigned short)((cv.u + 0x7FFFu + ((cv.u >> 16) & 1u)) >> 16);
}

__device__ __forceinline__ bf16 f2b(float f) {
    unsigned short us = f2b_bits(f);
    bf16 out; __builtin_memcpy(&out, &us, 2);
    return out;
}

__device__ __forceinline__ float sigm(float x) { return 1.f / (1.f + __expf(-x)); }
__device__ __forceinline__ float tanh_c(float x) {
    float cl = fminf(fmaxf(x, -20.f), 20.f);
    float e2 = __expf(2.f * cl);
    return (e2 - 1.f) / (e2 + 1.f);
}

// ---------------- dtype probe ----------------
__global__ void k_flag(const void* __restrict__ fnode, int* __restrict__ flag) {
    if (threadIdx.x == 0 && blockIdx.x == 0) {
        const unsigned short* u = (const unsigned short*)fnode;
        int cnt = 0;
        for (int i = 0; i < 64; i++) {
            unsigned short us = u[2 * i];
            unsigned ex = (us >> 7) & 0xFF;
            if (us == 0 || (ex >= 105 && ex <= 134)) cnt++;
        }
        *flag = (cnt >= 48) ? 1 : 0;
    }
}

// ---------------- cast fnode -> f32 ----------------
__global__ void k_cast(const void* __restrict__ in, float* __restrict__ out, int n,
                       const int* __restrict__ flag) {
    int bf = *flag;
    int i = blockIdx.x * 256 + threadIdx.x;
    if (i < n) out[i] = ldw(in, i, bf);
}

// ---------------- GEMM: C[4096 x 256] = A[4096 x K] * W[256 x K]^T (+bias) ----------------
__global__ __launch_bounds__(256) void k_gemm_nt(
    const float* __restrict__ A, const void* __restrict__ W, size_t woff,
    const void* __restrict__ bias, size_t boff, int has_bias,
    float* __restrict__ C, int K, const int* __restrict__ flag)
{
    int bf = *flag;
    __shared__ float Wl[256 * 33];
    __shared__ float Al[32 * 20];
    int a0 = blockIdx.x * 16;
    int c  = threadIdx.x;
    float acc[16];
#pragma unroll
    for (int i = 0; i < 16; i++) acc[i] = 0.f;

    for (int k0 = 0; k0 < K; k0 += 32) {
        __syncthreads();
        for (int i = threadIdx.x; i < 256 * 32; i += 256) {
            int c2 = i >> 5, kk = i & 31, k = k0 + kk;
            Wl[c2 * 33 + kk] = (k < K) ? ldw(W, woff + (size_t)c2 * K + k, bf) : 0.f;
        }
        for (int i = threadIdx.x; i < 512; i += 256) {
            int aa = i >> 5, kk = i & 31, k = k0 + kk;
            Al[kk * 20 + aa] = (k < K) ? A[(size_t)(a0 + aa) * K + k] : 0.f;
        }
        __syncthreads();
#pragma unroll
        for (int kk = 0; kk < 32; kk++) {
            float w = Wl[c * 33 + kk];
            const float4* ap = (const float4*)&Al[kk * 20];
            float4 a01 = ap[0], a23 = ap[1], a45 = ap[2], a67 = ap[3];
            acc[0]  += a01.x * w; acc[1]  += a01.y * w; acc[2]  += a01.z * w; acc[3]  += a01.w * w;
            acc[4]  += a23.x * w; acc[5]  += a23.y * w; acc[6]  += a23.z * w; acc[7]  += a23.w * w;
            acc[8]  += a45.x * w; acc[9]  += a45.y * w; acc[10] += a45.z * w; acc[11] += a45.w * w;
            acc[12] += a67.x * w; acc[13] += a67.y * w; acc[14] += a67.z * w; acc[15] += a67.w * w;
        }
    }
    float bv = has_bias ? ldw(bias, boff + c, bf) : 0.f;
#pragma unroll
    for (int i = 0; i < 16; i++) C[(size_t)(a0 + i) * 256 + c] = acc[i] + bv;
}

// ---------------- transpose x (4096x256) -> xT (256x4096) ----------------
__global__ __launch_bounds__(256) void k_xpose(const float* __restrict__ x, float* __restrict__ xT) {
    __shared__ float tl[32][33];
    int bx = blockIdx.x, by = blockIdx.y;
    int tx = threadIdx.x & 31, ty = threadIdx.x >> 5;
#pragma unroll
    for (int i = 0; i < 4; i++)
        tl[ty + i * 8][tx] = x[(size_t)(bx * 32 + ty + i * 8) * 256 + by * 32 + tx];
    __syncthreads();
#pragma unroll
    for (int i = 0; i < 4; i++)
        xT[(size_t)(by * 32 + ty + i * 8) * NA + bx * 32 + tx] = tl[tx][ty + i * 8];
}

// ---------------- build bf16 k-tiled hmess: hmB[kb][m][8], kb<36 ----------------
__global__ __launch_bounds__(256) void k_hmess_b(
    const float* __restrict__ x, const void* __restrict__ fmess,
    unsigned short* __restrict__ hmB, const int* __restrict__ flag)
{
    int bf = *flag;
    const int mb = blockIdx.x * 32;
    const int kc = blockIdx.y;     // 0..8
    const int k0 = kc * 32;
    __shared__ float tl[32][33];
    __shared__ int srcs[32];
    const int tid = threadIdx.x;
    if (tid < 32) {
        int s = (int)ldw(fmess, (size_t)(mb + tid) * 8, bf);
        srcs[tid] = min(max(s, 0), NA - 1);
    }
    __syncthreads();
    {
        const int ml = tid >> 3, kg = (tid & 7) * 4;
        if (kc < 8) {
            const float4 v = *(const float4*)&x[(size_t)srcs[ml] * 256 + k0 + kg];
            tl[ml][kg] = v.x; tl[ml][kg + 1] = v.y; tl[ml][kg + 2] = v.z; tl[ml][kg + 3] = v.w;
        } else {
#pragma unroll
            for (int j = 0; j < 4; j++) {
                int k = k0 + kg + j;
                float v = (k < 262) ? ldw(fmess, (size_t)(mb + ml) * 8 + 2 + (k - 256), bf) : 0.f;
                tl[ml][kg + j] = v;
            }
        }
    }
    __syncthreads();
    {
        const int kl = tid >> 3;
        const int mg = (tid & 7) * 4;
        const int kb = kc * 4 + (kl >> 3);
        const int j  = kl & 7;
#pragma unroll
        for (int i = 0; i < 4; i++)
            hmB[((size_t)kb * NM + mb + mg + i) * 8 + j] = f2b_bits(tl[mg + i][kl]);
    }
}

// ---------------- mol membership map ----------------
__global__ void k_molmap(const int* __restrict__ scopes, int nmol, int* __restrict__ molid) {
    int a = blockIdx.x * 256 + threadIdx.x;
    if (a >= NA) return;
    int mid = -1;
    for (int s2 = 0; s2 < nmol; s2++) {
        int st = scopes[2 * s2], ln = scopes[2 * s2 + 1];
        if (a >= st && a < st + ln) mid = s2;
    }
    molid[a] = mid;
}

// ---------------- MFMA precompute of r1/az/ah + fused depth-1 h1 ----------------
// grid (NM/128, tch); block 256 = 4 waves; wave computes 32d x 32m for all 3 mats.
__global__ __launch_bounds__(256) void k_pre_mfma(
    const unsigned short* __restrict__ hmB,
    const void* __restrict__ Wr_w, const void* __restrict__ Wz_w, const void* __restrict__ Wh_w,
    const void* __restrict__ Ur_b, const void* __restrict__ Wz_b, const void* __restrict__ Wh_b,
    int t0, float* __restrict__ r1, float* __restrict__ az, float* __restrict__ ah,
    float* __restrict__ h1, const int* __restrict__ flag)
{
    int bf = *flag;
    const int ti = blockIdx.y, t = t0 + ti;
    __shared__ unsigned short WL[3 * 32 * WLD];
    __shared__ float BL[3 * 32];
    __shared__ float TB[4][32 * 37];
    for (int i = threadIdx.x; i < 3 * 32 * WLD; i += 256) {
        int mt = i / (32 * WLD);
        int rr = i - mt * (32 * WLD);
        int d = rr / WLD, k = rr - d * WLD;
        unsigned short v = 0;
        if (k < 262) {
            size_t idx;
            const void* W;
            if (mt == 0)      { W = Wr_w; idx = ((size_t)t * 32 + d) * 262 + k; }
            else if (mt == 1) { W = Wz_w; idx = ((size_t)t * 32 + d) * 294 + k; }
            else              { W = Wh_w; idx = ((size_t)t * 32 + d) * 294 + k; }
            if (bf) v = ((const unsigned short*)W)[idx];
            else    v = f2b_bits(((const float*)W)[idx]);
        }
        WL[i] = v;
    }
    if (threadIdx.x < 96) {
        int mt = threadIdx.x >> 5, d = threadIdx.x & 31;
        const void* B = (mt == 0) ? Ur_b : (mt == 1) ? Wz_b : Wh_b;
        BL[threadIdx.x] = ldw(B, t * 32 + d, bf);
    }
    __syncthreads();
    const int w = threadIdx.x >> 6, lane = threadIdx.x & 63;
    const int col = lane & 15, g = lane >> 4;
    const int m0 = blockIdx.x * 128 + w * 32;

    f32x4 acc[3][2][2];
#pragma unroll
    for (int mt = 0; mt < 3; mt++)
#pragma unroll
        for (int dt = 0; dt < 2; dt++)
#pragma unroll
            for (int nt = 0; nt < 2; nt++) {
                acc[mt][dt][nt][0] = 0.f; acc[mt][dt][nt][1] = 0.f;
                acc[mt][dt][nt][2] = 0.f; acc[mt][dt][nt][3] = 0.f;
            }

    for (int ks = 0; ks < 9; ks++) {
        const int kb = ks * 4 + g;
        bh8 bfrag[2];
#pragma unroll
        for (int nt = 0; nt < 2; nt++)
            bfrag[nt] = *(const bh8*)&hmB[((size_t)kb * NM + m0 + nt * 16 + col) * 8];
        bh8 afrag[3][2];
#pragma unroll
        for (int mt = 0; mt < 3; mt++)
#pragma unroll
            for (int dt = 0; dt < 2; dt++)
                afrag[mt][dt] = *(const bh8*)&WL[mt * 32 * WLD + (dt * 16 + col) * WLD + ks * 32 + g * 8];
#pragma unroll
        for (int mt = 0; mt < 3; mt++)
#pragma unroll
            for (int dt = 0; dt < 2; dt++)
#pragma unroll
            for (int nt = 0; nt < 2; nt++)
                acc[mt][dt][nt] = __builtin_amdgcn_mfma_f32_16x16x32_bf16(
                    afrag[mt][dt], bfrag[nt], acc[mt][dt][nt], 0, 0, 0);
    }
#pragma unroll
    for (int mt = 0; mt < 3; mt++) {
        float* out = (mt == 0) ? r1 : (mt == 1) ? az : ah;
#pragma unroll
        for (int dt = 0; dt < 2; dt++)
#pragma unroll
            for (int r = 0; r < 4; r++) {
                int d = dt * 16 + g * 4 + r;
                float b = BL[mt * 32 + d];
#pragma unroll
                for (int nt = 0; nt < 2; nt++)
                    out[(size_t)(ti * 32 + d) * NM + m0 + nt * 16 + col] = acc[mt][dt][nt][r] + b;
            }
    }
    // fused depth-1 step: h1 = sigmoid(az)*tanh(ah)*mask
#pragma unroll
    for (int dt = 0; dt < 2; dt++)
#pragma unroll
        for (int nt = 0; nt < 2; nt++)
#pragma unroll
            for (int r = 0; r < 4; r++) {
                int d = dt * 16 + g * 4 + r;
                int mlocal = nt * 16 + col;
                float za = acc[1][dt][nt][r] + BL[32 + d];
                float pa = acc[2][dt][nt][r] + BL[64 + d];
                float hv = sigm(za) * tanh_c(pa);
                if (m0 + mlocal == 0) hv = 0.f;
                TB[w][mlocal * 37 + d] = hv;
            }
    __builtin_amdgcn_wave_barrier();
    float* ho = h1 + ((size_t)ti * NM + m0) * 32;
#pragma unroll
    for (int i = 0; i < 16; i++) {
        int idx = i * 64 + lane;
        ho[idx] = TB[w][(idx >> 5) * 37 + (idx & 31)];
    }
}

// ---------------- MFMA GRU depth step ----------------
// grid (NM/64, tch); block 256 = 4 waves x 16 messages; h layout [(ti*NM+m)*32+d]
__global__ __launch_bounds__(256) void k_step_m(
    const float* __restrict__ h_in, float* __restrict__ h_out,
    const float* __restrict__ r1, const float* __restrict__ az, const float* __restrict__ ah,
    const int* __restrict__ bgraph,
    const void* __restrict__ Ur_w, const void* __restrict__ Wz_w, const void* __restrict__ Wh_w,
    int t0, const int* __restrict__ flag)
{
    int bf = *flag;
    const int ti = blockIdx.y, t = t0 + ti;
    __shared__ unsigned short WS[3 * 32 * 40];      // Ur / Wz2 / Wh2, [d][40]
    __shared__ unsigned short HB[4][96 * 40];       // per-wave gathered h rows (bf16)
    __shared__ unsigned short SR[4][2 * 16 * 40];   // per-wave sumh / rh (bf16) [m][40]
    __shared__ float TB[4][16 * 37];                // per-wave output transpose
    for (int i = threadIdx.x; i < 3 * 32 * 32; i += 256) {
        int mt = i >> 10, rr = i & 1023, d = rr >> 5, j = rr & 31;
        float v;
        if (mt == 0)      v = ldw(Ur_w, ((size_t)t * 32 + d) * 32 + j, bf);
        else if (mt == 1) v = ldw(Wz_w, ((size_t)t * 32 + d) * 294 + 262 + j, bf);
        else              v = ldw(Wh_w, ((size_t)t * 32 + d) * 294 + 262 + j, bf);
        WS[(mt * 32 + d) * 40 + j] = f2b_bits(v);
    }
    __syncthreads();
    const int w = threadIdx.x >> 6, lane = threadIdx.x & 63;
    const int c = lane & 15, g = lane >> 4;
    const int m0 = blockIdx.x * 64 + w * 16;
    const float* hbase = h_in + (size_t)ti * NM * 32;
    unsigned short* hb = &HB[w][0];

    // hoisted A-fragments (row = dt*16 + c, k = g*8..g*8+7)
    bh8 aU[2], aZ[2], aH[2];
#pragma unroll
    for (int dt = 0; dt < 2; dt++) {
        aU[dt] = *(const bh8*)&WS[(0 * 32 + dt * 16 + c) * 40 + g * 8];
        aZ[dt] = *(const bh8*)&WS[(1 * 32 + dt * 16 + c) * 40 + g * 8];
        aH[dt] = *(const bh8*)&WS[(2 * 32 + dt * 16 + c) * 40 + g * 8];
    }

    // gather: 96 rows (col = nb*16 + ml), each row = 32 f32 -> 32 bf16 in LDS
    for (int rr = lane; rr < 96; rr += 64) {
        int nb = rr >> 4, ml = rr & 15;
        int m = m0 + ml;
        int bg = bgraph[m * 6 + nb];
        bg = min(max(bg, 0), NM - 1);
        const float4* hr = (const float4*)(hbase + (size_t)bg * 32);
#pragma unroll
        for (int ii = 0; ii < 4; ii++) {
            float4 a = hr[2 * ii], b = hr[2 * ii + 1];
            us8 o;
            o[0] = f2b_bits(a.x); o[1] = f2b_bits(a.y); o[2] = f2b_bits(a.z); o[3] = f2b_bits(a.w);
            o[4] = f2b_bits(b.x); o[5] = f2b_bits(b.y); o[6] = f2b_bits(b.z); o[7] = f2b_bits(b.w);
            *(us8*)&hb[rr * 40 + ii * 8] = o;
        }
    }
    __builtin_amdgcn_wave_barrier();

    // hoisted r1 (C-frag layout: row d = dt*16+4g+r, col m = m0+c)
    float r1v[2][4];
#pragma unroll
    for (int dt = 0; dt < 2; dt++)
#pragma unroll
        for (int r = 0; r < 4; r++)
            r1v[dt][r] = r1[(size_t)(ti * 32 + dt * 16 + 4 * g + r) * NM + m0 + c];

    const f32x4 zf = {0.f, 0.f, 0.f, 0.f};
    f32x4 sumA[2] = {zf, zf}, rhA[2] = {zf, zf};

    for (int nb = 0; nb < 6; nb++) {
        bh8 bfr = *(const bh8*)&hb[(nb * 16 + c) * 40 + g * 8];
        f32x4 c0 = __builtin_amdgcn_mfma_f32_16x16x32_bf16(aU[0], bfr, zf, 0, 0, 0);
        f32x4 c1 = __builtin_amdgcn_mfma_f32_16x16x32_bf16(aU[1], bfr, zf, 0, 0, 0);
        us4 hv0 = *(const us4*)&hb[(nb * 16 + c) * 40 + 4 * g];
        us4 hv1 = *(const us4*)&hb[(nb * 16 + c) * 40 + 16 + 4 * g];
#pragma unroll
        for (int r = 0; r < 4; r++) {
            float h0 = bb(hv0[r]), h1v = bb(hv1[r]);
            float rr0 = sigm(r1v[0][r] + c0[r]);
            float rr1 = sigm(r1v[1][r] + c1[r]);
            sumA[0][r] += h0;        sumA[1][r] += h1v;
            rhA[0][r] += rr0 * h0;   rhA[1][r] += rr1 * h1v;
        }
    }

    // write sumh/rh (bf16) for the tail matmuls; per-wave region, wave-ordered
    unsigned short* srS = &SR[w][0];
    unsigned short* srR = &SR[w][16 * 40];
#pragma unroll
    for (int dt = 0; dt < 2; dt++) {
        us4 oS, oR;
#pragma unroll
        for (int r = 0; r < 4; r++) { oS[r] = f2b_bits(sumA[dt][r]); oR[r] = f2b_bits(rhA[dt][r]); }
        *(us4*)&srS[c * 40 + dt * 16 + 4 * g] = oS;
        *(us4*)&srR[c * 40 + dt * 16 + 4 * g] = oR;
    }
    __builtin_amdgcn_wave_barrier();

    bh8 bS = *(const bh8*)&srS[c * 40 + g * 8];
    bh8 bR = *(const bh8*)&srR[c * 40 + g * 8];
    f32x4 z0 = __builtin_amdgcn_mfma_f32_16x16x32_bf16(aZ[0], bS, zf, 0, 0, 0);
    f32x4 z1 = __builtin_amdgcn_mfma_f32_16x16x32_bf16(aZ[1], bS, zf, 0, 0, 0);
    f32x4 p0 = __builtin_amdgcn_mfma_f32_16x16x32_bf16(aH[0], bR, zf, 0, 0, 0);
    f32x4 p1 = __builtin_amdgcn_mfma_f32_16x16x32_bf16(aH[1], bR, zf, 0, 0, 0);

    const int m = m0 + c;
    const float msk = (m == 0) ? 0.f : 1.f;
#pragma unroll
    for (int dt = 0; dt < 2; dt++) {
        f32x4 zt = dt ? z1 : z0;
        f32x4 pt = dt ? p1 : p0;
#pragma unroll
        for (int r = 0; r < 4; r++) {
            int d = dt * 16 + 4 * g + r;
            float zacc = az[(size_t)(ti * 32 + d) * NM + m] + zt[r];
            float pacc = ah[(size_t)(ti * 32 + d) * NM + m] + pt[r];
            float zz = sigm(zacc);
            float th = tanh_c(pacc);
            TB[w][c * 37 + d] = ((1.f - zz) * sumA[dt][r] + zz * th) * msk;
        }
    }
    __builtin_amdgcn_wave_barrier();
    float* ho = h_out + ((size_t)ti * NM + m0) * 32;
#pragma unroll
    for (int i = 0; i < 8; i++) {
        int idx = i * 64 + lane;
        ho[idx] = TB[w][(idx >> 5) * 37 + (idx & 31)];
    }
}

// ---------------- outs = relu([x, nei] @ Wo^T + b) * node_mask, scattered into qkv ----------------
// grid (NA/64, tch); block 256 = 64 atoms x 4 d-quarters
__global__ __launch_bounds__(256) void k_outs(
    const float* __restrict__ xT, const float* __restrict__ h,
    const int* __restrict__ agraph, const void* __restrict__ Wo_w, const void* __restrict__ Wo_b,
    int t0, float* __restrict__ qkv, const int* __restrict__ flag)
{
    int bf = *flag;
    const int ti = blockIdx.y, t = t0 + ti;
    const int hh = t / 3, s2 = t - 3 * hh;
    __shared__ float WL[32 * 297];
    __shared__ float tb[4][16 * 33];
    for (int i = threadIdx.x; i < 32 * 297; i += 256) {
        int d = i / 297, k = i - d * 297;
        WL[i] = (k < 288) ? ldw(Wo_w, ((size_t)t * 32 + d) * 288 + k, bf) : 0.f;
    }
    __syncthreads();
    const int q = threadIdx.x & 3, al = threadIdx.x >> 2;
    const int a = blockIdx.x * 64 + al;
    const int d0 = q * 8;
    float nei[32];
#pragma unroll
    for (int j = 0; j < 32; j++) nei[j] = 0.f;
#pragma unroll
    for (int nb = 0; nb < 6; nb++) {
        int ag = agraph[a * 6 + nb];
        ag = min(max(ag, 0), NM - 1);
        const float* hr = h + ((size_t)ti * NM + ag) * 32;
#pragma unroll
        for (int j4 = 0; j4 < 32; j4 += 4) {
            float4 v = *(const float4*)&hr[j4];
            nei[j4] += v.x; nei[j4 + 1] += v.y; nei[j4 + 2] += v.z; nei[j4 + 3] += v.w;
        }
    }
    float acc[8];
#pragma unroll
    for (int dd = 0; dd < 8; dd++) acc[dd] = ldw(Wo_b, t * 32 + d0 + dd, bf);
    for (int kc = 0; kc < 8; kc++) {
        float xv[32];
#pragma unroll
        for (int kk = 0; kk < 32; kk++) xv[kk] = xT[(size_t)(kc * 32 + kk) * NA + a];
#pragma unroll
        for (int dd = 0; dd < 8; dd++) {
            const float* wp = &WL[(d0 + dd) * 297 + kc * 32];
#pragma unroll
            for (int kk = 0; kk < 32; kk++) acc[dd] += xv[kk] * wp[kk];
        }
    }
    const int wv = threadIdx.x >> 6, l = threadIdx.x & 63, aw = al & 15;
#pragma unroll
    for (int dd = 0; dd < 8; dd++) {
        const float* wp = &WL[(d0 + dd) * 297 + 256];
        float s = acc[dd];
#pragma unroll
        for (int j = 0; j < 32; j++) s += nei[j] * wp[j];
        s = fmaxf(s, 0.f);
        if (a == 0) s = 0.f;
        tb[wv][aw * 33 + d0 + dd] = s;
    }
    __syncthreads();
    int abase = blockIdx.x * 64 + wv * 16;
#pragma unroll
    for (int i = 0; i < 8; i++) {
        int idx = i * 64 + l;
        int mm = idx >> 5, d = idx & 31;
        float v = tb[wv][mm * 33 + d];
        size_t dst;
        if (s2 == 0) dst = (size_t)(abase + mm) * 256 + hh * 32 + d;
        else dst = (size_t)s2 * 1048576 + (size_t)hh * 131072 + (size_t)(abase + mm) * 32 + d;
        qkv[dst] = v;
    }
}

// ---------------- per-molecule 32x32 attention block ----------------
__global__ __launch_bounds__(64) void k_attn_mol(
    const float* __restrict__ Qp, const float* __restrict__ Kp, const float* __restrict__ Vp,
    const int* __restrict__ scopes, float* __restrict__ ctx)
{
    int mol = blockIdx.x;
    int g = threadIdx.x >> 5;
    int head = blockIdx.y * 2 + g;
    int lane = threadIdx.x & 31;
    int start = scopes[2 * mol];
    int len = min(scopes[2 * mol + 1], 32);
    if (len <= 0) return;
    __shared__ float Ql[2][32 * 36], Kl[2][32 * 36], Vl[2][32 * 36], Pl[2][32 * 36];
    for (int i = 0; i < len; i++) {
        if (start + i >= NA) break;
        size_t base = (size_t)(start + i) * 256 + head * 32 + lane;
        Ql[g][i * 36 + lane] = Qp[base];
        Kl[g][i * 36 + lane] = Kp[base];
        Vl[g][i * 36 + lane] = Vp[base];
    }
    for (int i = len; i < 32; i++) { Vl[g][i * 36 + lane] = 0.f; Kl[g][i * 36 + lane] = 0.f; }
    float kreg[32];
#pragma unroll
    for (int d2 = 0; d2 < 32; d2++) kreg[d2] = Kl[g][lane * 36 + d2];
    const float scale = 0.17677669529663687f;
    for (int i = 0; i < len; i++) {
        float s = 0.f;
#pragma unroll
        for (int d2 = 0; d2 < 32; d2++) s += Ql[g][i * 36 + d2] * kreg[d2];
        s *= scale;
        if (lane >= len) s = -1e30f;
        float mx = s;
#pragma unroll
        for (int off = 16; off > 0; off >>= 1) mx = fmaxf(mx, __shfl_xor(mx, off, 32));
        float p = __expf(s - mx);
        if (lane >= len) p = 0.f;
        float sum = p;
#pragma unroll
        for (int off = 16; off > 0; off >>= 1) sum += __shfl_xor(sum, off, 32);
        Pl[g][i * 36 + lane] = p / sum;
    }
    for (int i = 0; i < len; i++) {
        if (start + i >= NA) break;
        float acc = 0.f;
#pragma unroll
        for (int j = 0; j < 32; j++) acc += Pl[g][i * 36 + j] * Vl[g][j * 36 + lane];
        ctx[(size_t)(start + i) * 256 + head * 32 + lane] = acc;
    }
}

// ---------------- column sums of Vp ----------------
__global__ __launch_bounds__(256) void k_colsum(
    const float* __restrict__ Vp, float* __restrict__ partial)
{
    int b = blockIdx.x, c = threadIdx.x;
    float a0 = 0.f, a1 = 0.f, a2 = 0.f, a3 = 0.f;
    for (int j = 0; j < 32; j++) {
        const float* rp = Vp + ((size_t)b * 128 + j * 4) * 256 + c;
        a0 += rp[0]; a1 += rp[256]; a2 += rp[512]; a3 += rp[768];
    }
    partial[b * 256 + c] = a0 + a1 + a2 + a3;
}

// ---------------- degenerate attention rows ----------------
__global__ __launch_bounds__(256) void k_fill(
    const float* __restrict__ Vp, const float* __restrict__ partial,
    const int* __restrict__ molid, float* __restrict__ ctx)
{
    int a = blockIdx.x, c = threadIdx.x;
    if (molid[a] >= 0) return;
    float v;
    if (a == 0) v = Vp[c];
    else {
        float s = 0.f;
#pragma unroll
        for (int b = 0; b < 32; b++) s += partial[b * 256 + c];
        v = s * (1.f / 4096.f);
    }
    ctx[(size_t)a * 256 + c] = v;
}

// ---------------- layernorm -> out ----------------
__global__ __launch_bounds__(256) void k_ln(
    const float* __restrict__ xo, const void* __restrict__ g_, const void* __restrict__ b_,
    void* __restrict__ out, const int* __restrict__ flag)
{
    int bf = *flag;
    int a = blockIdx.x, c = threadIdx.x;
    float v = xo[(size_t)a * 256 + c];
    __shared__ float red[4], red2[4];
    float s = v;
#pragma unroll
    for (int off = 32; off > 0; off >>= 1) s += __shfl_down(s, off);
    int w = threadIdx.x >> 6, ln2 = threadIdx.x & 63;
    if (ln2 == 0) red[w] = s;
    __syncthreads();
    float mu = (red[0] + red[1] + red[2] + red[3]) * (1.f / 256.f);
    float dv = v - mu;
    float sq = dv * dv;
#pragma unroll
    for (int off = 32; off > 0; off >>= 1) sq += __shfl_down(sq, off);
    if (ln2 == 0) red2[w] = sq;
    __syncthreads();
    float var = (red2[0] + red2[1] + red2[2] + red2[3]) * (1.f / 256.f);
    float y = dv * rsqrtf(var + 1e-5f) * ldw(g_, c, bf) + ldw(b_, c, bf);
    size_t idx = (size_t)a * 256 + c;
    if (bf) ((bf16*)out)[idx] = f2b(y);
    else    ((float*)out)[idx] = y;
}

extern "C" void kernel_launch(void* const* d_in, const int* in_sizes, int n_in,
                              void* d_out, int out_size, void* d_ws, size_t ws_size,
                              hipStream_t stream)
{
    const void* fnode  = d_in[0];
    const void* fmess  = d_in[1];
    const int*  agraph = (const int*)d_in[2];
    const int*  bgraph = (const int*)d_in[3];
    const int*  scopes = (const int*)d_in[4];
    const void* W_i_w  = d_in[5];
    const void* Wz_w   = d_in[6];
    const void* Wz_b   = d_in[7];
    const void* Wr_w   = d_in[8];
    const void* Ur_w   = d_in[9];
    const void* Ur_b   = d_in[10];
    const void* Wh_w   = d_in[11];
    const void* Wh_b   = d_in[12];
    const void* Wo_w   = d_in[13];
    const void* Wo_b   = d_in[14];
    const void* attn_w = d_in[15];
    const void* attn_b = d_in[16];
    const void* aow    = d_in[17];
    const void* bww    = d_in[18];
    const void* ln_g   = d_in[19];
    const void* ln_b   = d_in[20];
    int nmol = in_sizes[4] / 2;

    // -------- workspace layout (f32 units); tch chosen from ws_size --------
    const size_t REGA = 3145728;
    const size_t fixedF = 1048576 + REGA + 3 * 1048576 + NA + 1 + 32 * 256;
    int tch = 2;
    if (ws_size / 4 >= fixedF + 5ull * 8 * 32 * NM + 1024) tch = 8;
    else if (ws_size / 4 >= fixedF + 5ull * 4 * 32 * NM + 1024) tch = 4;
    const size_t CS = (size_t)tch * 32 * NM;

    float* p   = (float*)d_ws;
    float* xT  = p;                    p += 1048576;
    float* regA = p;                   p += REGA;
    float* cs  = p;                    p += 5 * CS;
    float* qkv = p;                    p += 3 * 1048576;
    int*   molid = (int*)p;            p += NA;
    int*   dflag = (int*)p;            p += 1;
    float* partial = p;                p += 32 * 256;

    unsigned short* hmB = (unsigned short*)regA;
    float* ctx = regA;
    float* y1  = regA + 1048576;
    float* xo  = regA + 2097152;

    float* r1 = cs;
    float* az = cs + CS;
    float* ah = cs + 2 * CS;
    float* h0 = cs + 3 * CS;
    float* h1 = cs + 4 * CS;
    float* fnode_f = qkv;
    float* x       = qkv + 524288;
    float* Qp  = cs;
    float* Kp  = cs + 1048576;
    float* Vp  = cs + 2097152;

    k_flag<<<1, 64, 0, stream>>>(fnode, dflag);
    k_cast<<<(401408 + 255) / 256, 256, 0, stream>>>(fnode, fnode_f, 401408, dflag);
    k_gemm_nt<<<256, 256, 0, stream>>>(fnode_f, W_i_w, 0, nullptr, 0, 0, x, 98, dflag);
    k_xpose<<<dim3(128, 8), 256, 0, stream>>>(x, xT);
    k_hmess_b<<<dim3(NM / 32, 9), 256, 0, stream>>>(x, fmess, hmB, dflag);
    k_molmap<<<(NA + 255) / 256, 256, 0, stream>>>(scopes, nmol, molid);

    for (int tc = 0; tc < 24 / tch; tc++) {
        int t0 = tc * tch;
        k_pre_mfma<<<dim3(NM / 128, tch), 256, 0, stream>>>(
            hmB, Wr_w, Wz_w, Wh_w, Ur_b, Wz_b, Wh_b, t0, r1, az, ah, h1, dflag);
        k_step_m<<<dim3(NM / 64, tch), 256, 0, stream>>>(h1, h0, r1, az, ah, bgraph, Ur_w, Wz_w, Wh_w, t0, dflag);
        k_step_m<<<dim3(NM / 64, tch), 256, 0, stream>>>(h0, h1, r1, az, ah, bgraph, Ur_w, Wz_w, Wh_w, t0, dflag);
        k_outs<<<dim3(NA / 64, tch), 256, 0, stream>>>(xT, h1, agraph, Wo_w, Wo_b, t0, qkv, dflag);
    }

    k_gemm_nt<<<256, 256, 0, stream>>>(qkv,           attn_w, 0,      attn_b, 0,   1, Qp, 256, dflag);
    k_gemm_nt<<<256, 256, 0, stream>>>(qkv + 1048576, attn_w, 65536,  attn_b, 256, 1, Kp, 256, dflag);
    k_gemm_nt<<<256, 256, 0, stream>>>(qkv + 2097152, attn_w, 131072, attn_b, 512, 1, Vp, 256, dflag);

    k_attn_mol<<<dim3(nmol, 4), 64, 0, stream>>>(Qp, Kp, Vp, scopes, ctx);
    k_colsum<<<32, 256, 0, stream>>>(Vp, partial);
    k_fill<<<NA, 256, 0, stream>>>(Vp, partial, molid, ctx);

    k_gemm_nt<<<256, 256, 0, stream>>>(ctx, aow, 0, nullptr, 0, 0, y1, 256, dflag);
    k_gemm_nt<<<256, 256, 0, stream>>>(y1,  bww, 0, nullptr, 0, 0, xo, 256, dflag);
    k_ln<<<NA, 256, 0, stream>>>(xo, ln_g, ln_b, d_out, dflag);
    (void)ws_size; (void)out_size; (void)n_in;
}

// Round 8
// 841.724 us; speedup vs baseline: 4.3564x; 1.6243x over previous
//
#include <hip/hip_runtime.h>
#include <hip/hip_bf16.h>

typedef __hip_bfloat16 bf16;
typedef __attribute__((ext_vector_type(8))) short bh8;             // 8 bf16 (4 VGPRs)
typedef __attribute__((ext_vector_type(4))) float f32x4;
typedef __attribute__((ext_vector_type(8))) unsigned short us8;
typedef __attribute__((ext_vector_type(4))) unsigned short us4;

#define NA    4096
#define NM    16384

__device__ __forceinline__ float b2f(bf16 v) { return __bfloat162float(v); }

__device__ __forceinline__ float bb(unsigned short u) {
    union { unsigned u; float f; } c; c.u = ((unsigned)u) << 16; return c.f;
}

__device__ __forceinline__ float ldw(const void* p, size_t i, int bf) {
    if (bf) return b2f(((const bf16*)p)[i]);
    return ((const float*)p)[i];
}

__device__ __forceinline__ unsigned short f2b_bits(float f) {
    union { unsigned u; float ff; } cv; cv.ff = f;
    return (unsigned short)((cv.u + 0x7FFFu + ((cv.u >> 16) & 1u)) >> 16);
}

__device__ __forceinline__ bf16 f2b(float f) {
    unsigned short us = f2b_bits(f);
    bf16 out; __builtin_memcpy(&out, &us, 2);
    return out;
}

__device__ __forceinline__ float sigm(float x) { return 1.f / (1.f + __expf(-x)); }
__device__ __forceinline__ float tanh_c(float x) {
    float cl = fminf(fmaxf(x, -20.f), 20.f);
    float e2 = __expf(2.f * cl);
    return (e2 - 1.f) / (e2 + 1.f);
}

// ---------------- dtype probe ----------------
__global__ void k_flag(const void* __restrict__ fnode, int* __restrict__ flag) {
    if (threadIdx.x == 0 && blockIdx.x == 0) {
        const unsigned short* u = (const unsigned short*)fnode;
        int cnt = 0;
        for (int i = 0; i < 64; i++) {
            unsigned short us = u[2 * i];
            unsigned ex = (us >> 7) & 0xFF;
            if (us == 0 || (ex >= 105 && ex <= 134)) cnt++;
        }
        *flag = (cnt >= 48) ? 1 : 0;
    }
}

// ---------------- generic weight pack: [rows x sstride] -> bf16 [rows x kpad] ----------------
__global__ void k_wpack(const void* __restrict__ src, int sstride, int ncopy, int kpad,
                        unsigned short* __restrict__ dst, const int* __restrict__ flag) {
    int r = blockIdx.x;
    int bf = *flag;
    for (int k = threadIdx.x; k < kpad; k += 256) {
        unsigned short v = 0;
        if (k < ncopy) {
            if (bf) v = ((const unsigned short*)src)[(size_t)r * sstride + k];
            else    v = f2b_bits(((const float*)src)[(size_t)r * sstride + k]);
        }
        dst[(size_t)r * kpad + k] = v;
    }
}

// ---------------- cast fnode -> f32 padded [4096][128] ----------------
__global__ void k_cast_pad(const void* __restrict__ in, float* __restrict__ out,
                           const int* __restrict__ flag) {
    int bf = *flag;
    int i = blockIdx.x * 256 + threadIdx.x;       // 4096*128
    int a = i >> 7, k = i & 127;
    out[i] = (k < 98) ? ldw(in, (size_t)a * 98 + k, bf) : 0.f;
}

// ---------------- MFMA GEMM: C[4096 x 256] = A[4096 x Kpad] * Wp[256 x Kpad]^T (+bias) ----------------
// Split-A hi/lo for f32-level accuracy.
__global__ __launch_bounds__(256) void k_gemm_m(
    const float* __restrict__ A, const unsigned short* __restrict__ Wp,
    const void* __restrict__ bias, size_t boff, int has_bias,
    float* __restrict__ C, int nks, const int* __restrict__ flag)
{
    const int Kpad = nks * 32;
    __shared__ float BLg[128];
    if (threadIdx.x < 128)
        BLg[threadIdx.x] = has_bias ? ldw(bias, boff + blockIdx.y * 128 + threadIdx.x, *flag) : 0.f;
    __syncthreads();
    const int w = threadIdx.x >> 6, lane = threadIdx.x & 63;
    const int col = lane & 15, g = lane >> 4;
    const int m = blockIdx.x * 64 + w * 16 + col;
    const int ch0 = blockIdx.y * 128;
    const f32x4 zf = {0.f, 0.f, 0.f, 0.f};
    f32x4 acc[8] = {zf, zf, zf, zf, zf, zf, zf, zf};
    for (int ks = 0; ks < nks; ks++) {
        const float4* ap = (const float4*)&A[(size_t)m * Kpad + ks * 32 + g * 8];
        float4 a0 = ap[0], a1 = ap[1];
        float av[8] = {a0.x, a0.y, a0.z, a0.w, a1.x, a1.y, a1.z, a1.w};
        bh8 hi, lo;
#pragma unroll
        for (int j = 0; j < 8; j++) {
            unsigned short h = f2b_bits(av[j]);
            hi[j] = (short)h;
            lo[j] = (short)f2b_bits(av[j] - bb(h));
        }
#pragma unroll
        for (int dt = 0; dt < 8; dt++) {
            bh8 wfr = *(const bh8*)&Wp[(size_t)(ch0 + dt * 16 + col) * Kpad + ks * 32 + g * 8];
            acc[dt] = __builtin_amdgcn_mfma_f32_16x16x32_bf16(wfr, hi, acc[dt], 0, 0, 0);
            acc[dt] = __builtin_amdgcn_mfma_f32_16x16x32_bf16(wfr, lo, acc[dt], 0, 0, 0);
        }
    }
#pragma unroll
    for (int dt = 0; dt < 8; dt++) {
        int cl = dt * 16 + g * 4;
        float4 o;
        o.x = acc[dt][0] + BLg[cl + 0];
        o.y = acc[dt][1] + BLg[cl + 1];
        o.z = acc[dt][2] + BLg[cl + 2];
        o.w = acc[dt][3] + BLg[cl + 3];
        *(float4*)&C[(size_t)m * 256 + ch0 + cl] = o;
    }
}

// ---------------- transpose x (4096x256) -> xT (256x4096) ----------------
__global__ __launch_bounds__(256) void k_xpose(const float* __restrict__ x, float* __restrict__ xT) {
    __shared__ float tl[32][33];
    int bx = blockIdx.x, by = blockIdx.y;
    int tx = threadIdx.x & 31, ty = threadIdx.x >> 5;
#pragma unroll
    for (int i = 0; i < 4; i++)
        tl[ty + i * 8][tx] = x[(size_t)(bx * 32 + ty + i * 8) * 256 + by * 32 + tx];
    __syncthreads();
#pragma unroll
    for (int i = 0; i < 4; i++)
        xT[(size_t)(by * 32 + ty + i * 8) * NA + bx * 32 + tx] = tl[tx][ty + i * 8];
}

// ---------------- build SPLIT hi/lo bf16 k-tiled hmess: hmB[kb][m][16] (8 hi, 8 lo), kb<36 ----------------
__global__ __launch_bounds__(256) void k_hmess_b(
    const float* __restrict__ x, const void* __restrict__ fmess,
    unsigned short* __restrict__ hmB, const int* __restrict__ flag)
{
    int bf = *flag;
    const int mb = blockIdx.x * 32;
    const int kc = blockIdx.y;     // 0..8
    const int k0 = kc * 32;
    __shared__ float tl[32][33];
    __shared__ int srcs[32];
    const int tid = threadIdx.x;
    if (tid < 32) {
        int s = (int)ldw(fmess, (size_t)(mb + tid) * 8, bf);
        srcs[tid] = min(max(s, 0), NA - 1);
    }
    __syncthreads();
    {
        const int ml = tid >> 3, kg = (tid & 7) * 4;
        if (kc < 8) {
            const float4 v = *(const float4*)&x[(size_t)srcs[ml] * 256 + k0 + kg];
            tl[ml][kg] = v.x; tl[ml][kg + 1] = v.y; tl[ml][kg + 2] = v.z; tl[ml][kg + 3] = v.w;
        } else {
#pragma unroll
            for (int j = 0; j < 4; j++) {
                int k = k0 + kg + j;
                float v = (k < 262) ? ldw(fmess, (size_t)(mb + ml) * 8 + 2 + (k - 256), bf) : 0.f;
                tl[ml][kg + j] = v;
            }
        }
    }
    __syncthreads();
    {
        const int kl = tid >> 3;
        const int mg = (tid & 7) * 4;
        const int kb = kc * 4 + (kl >> 3);
        const int j  = kl & 7;
#pragma unroll
        for (int i = 0; i < 4; i++) {
            float v = tl[mg + i][kl];
            unsigned short h = f2b_bits(v);
            unsigned short l = f2b_bits(v - bb(h));
            size_t base = ((size_t)kb * NM + mb + mg + i) * 16;
            hmB[base + j] = h;
            hmB[base + 8 + j] = l;
        }
    }
}

// ---------------- mol membership map ----------------
__global__ void k_molmap(const int* __restrict__ scopes, int nmol, int* __restrict__ molid) {
    int a = blockIdx.x * 256 + threadIdx.x;
    if (a >= NA) return;
    int mid = -1;
    for (int s2 = 0; s2 < nmol; s2++) {
        int st = scopes[2 * s2], ln = scopes[2 * s2 + 1];
        if (a >= st && a < st + ln) mid = s2;
    }
    molid[a] = mid;
}

// ---------------- MFMA precompute of r1/az/ah + fused depth-1 h1 (split-B, f32-accurate) ----------------
// grid (NM/128, tch); block 256 = 4 waves.
__global__ __launch_bounds__(256) void k_pre_mfma(
    const unsigned short* __restrict__ hmB, const unsigned short* __restrict__ gpack,
    const void* __restrict__ Ur_b, const void* __restrict__ Wz_b, const void* __restrict__ Wh_b,
    int t0, float* __restrict__ r1, float* __restrict__ az, float* __restrict__ ah,
    float* __restrict__ h1, const int* __restrict__ flag)
{
    int bf = *flag;
    const int ti = blockIdx.y, t = t0 + ti;
    __shared__ float BL[3 * 32];
    __shared__ float TB[4][32 * 37];
    if (threadIdx.x < 96) {
        int mt = threadIdx.x >> 5, d = threadIdx.x & 31;
        const void* B = (mt == 0) ? Ur_b : (mt == 1) ? Wz_b : Wh_b;
        BL[threadIdx.x] = ldw(B, t * 32 + d, bf);
    }
    __syncthreads();
    const int w = threadIdx.x >> 6, lane = threadIdx.x & 63;
    const int col = lane & 15, g = lane >> 4;
    const int m0 = blockIdx.x * 128 + w * 32;

    f32x4 acc[3][2][2];
#pragma unroll
    for (int mt = 0; mt < 3; mt++)
#pragma unroll
        for (int dt = 0; dt < 2; dt++)
#pragma unroll
            for (int nt = 0; nt < 2; nt++) {
                acc[mt][dt][nt][0] = 0.f; acc[mt][dt][nt][1] = 0.f;
                acc[mt][dt][nt][2] = 0.f; acc[mt][dt][nt][3] = 0.f;
            }

    for (int ks = 0; ks < 9; ks++) {
        const int kb = ks * 4 + g;
        bh8 bhi[2], blo[2];
#pragma unroll
        for (int nt = 0; nt < 2; nt++) {
            size_t base = ((size_t)kb * NM + m0 + nt * 16 + col) * 16;
            bhi[nt] = *(const bh8*)&hmB[base];
            blo[nt] = *(const bh8*)&hmB[base + 8];
        }
        bh8 afrag[3][2];
#pragma unroll
        for (int mt = 0; mt < 3; mt++)
#pragma unroll
            for (int dt = 0; dt < 2; dt++)
                afrag[mt][dt] = *(const bh8*)&gpack[
                    (size_t)(mt * 768 + t * 32 + dt * 16 + col) * 288 + ks * 32 + g * 8];
#pragma unroll
        for (int mt = 0; mt < 3; mt++)
#pragma unroll
            for (int dt = 0; dt < 2; dt++)
#pragma unroll
            for (int nt = 0; nt < 2; nt++) {
                acc[mt][dt][nt] = __builtin_amdgcn_mfma_f32_16x16x32_bf16(
                    afrag[mt][dt], bhi[nt], acc[mt][dt][nt], 0, 0, 0);
                acc[mt][dt][nt] = __builtin_amdgcn_mfma_f32_16x16x32_bf16(
                    afrag[mt][dt], blo[nt], acc[mt][dt][nt], 0, 0, 0);
            }
    }
#pragma unroll
    for (int mt = 0; mt < 3; mt++) {
        float* out = (mt == 0) ? r1 : (mt == 1) ? az : ah;
#pragma unroll
        for (int dt = 0; dt < 2; dt++)
#pragma unroll
            for (int r = 0; r < 4; r++) {
                int d = dt * 16 + g * 4 + r;
                float b = BL[mt * 32 + d];
#pragma unroll
                for (int nt = 0; nt < 2; nt++)
                    out[(size_t)(ti * 32 + d) * NM + m0 + nt * 16 + col] = acc[mt][dt][nt][r] + b;
            }
    }
    // fused depth-1 step: h1 = sigmoid(az)*tanh(ah)*mask
#pragma unroll
    for (int dt = 0; dt < 2; dt++)
#pragma unroll
        for (int nt = 0; nt < 2; nt++)
#pragma unroll
            for (int r = 0; r < 4; r++) {
                int d = dt * 16 + g * 4 + r;
                int mlocal = nt * 16 + col;
                float za = acc[1][dt][nt][r] + BL[32 + d];
                float pa = acc[2][dt][nt][r] + BL[64 + d];
                float hv = sigm(za) * tanh_c(pa);
                if (m0 + mlocal == 0) hv = 0.f;
                TB[w][mlocal * 37 + d] = hv;
            }
    __builtin_amdgcn_wave_barrier();
    float* ho = h1 + ((size_t)ti * NM + m0) * 32;
#pragma unroll
    for (int i = 0; i < 16; i++) {
        int idx = i * 64 + lane;
        ho[idx] = TB[w][(idx >> 5) * 37 + (idx & 31)];
    }
}

// ---------------- MFMA GRU depth step (f32 sumh/rh path, split tail) ----------------
// grid (NM/64, tch); block 256 = 4 waves x 16 messages; h layout [(ti*NM+m)*32+d]
__global__ __launch_bounds__(256) void k_step_m(
    const float* __restrict__ h_in, float* __restrict__ h_out,
    const float* __restrict__ r1, const float* __restrict__ az, const float* __restrict__ ah,
    const int* __restrict__ bgraph,
    const void* __restrict__ Ur_w, const void* __restrict__ Wz_w, const void* __restrict__ Wh_w,
    int t0, const int* __restrict__ flag)
{
    int bf = *flag;
    const int ti = blockIdx.y, t = t0 + ti;
    __shared__ unsigned short WS[3 * 32 * 40];      // Ur / Wz2 / Wh2, [d][40]
    __shared__ unsigned short HB[4][96 * 40];       // per-wave gathered h rows (bf16, for Ur MFMA)
    __shared__ unsigned short SR[4][4 * 16 * 40];   // per-wave Shi/Slo/Rhi/Rlo [m][40]
    __shared__ float TB[4][16 * 37];                // per-wave output transpose
    for (int i = threadIdx.x; i < 3 * 32 * 32; i += 256) {
        int mt = i >> 10, rr = i & 1023, d = rr >> 5, j = rr & 31;
        float v;
        if (mt == 0)      v = ldw(Ur_w, ((size_t)t * 32 + d) * 32 + j, bf);
        else if (mt == 1) v = ldw(Wz_w, ((size_t)t * 32 + d) * 294 + 262 + j, bf);
        else              v = ldw(Wh_w, ((size_t)t * 32 + d) * 294 + 262 + j, bf);
        WS[(mt * 32 + d) * 40 + j] = f2b_bits(v);
    }
    __syncthreads();
    const int w = threadIdx.x >> 6, lane = threadIdx.x & 63;
    const int c = lane & 15, g = lane >> 4;
    const int m0 = blockIdx.x * 64 + w * 16;
    const float* hbase = h_in + (size_t)ti * NM * 32;
    unsigned short* hb = &HB[w][0];

    bh8 aU[2], aZ[2], aH[2];
#pragma unroll
    for (int dt = 0; dt < 2; dt++) {
        aU[dt] = *(const bh8*)&WS[(0 * 32 + dt * 16 + c) * 40 + g * 8];
        aZ[dt] = *(const bh8*)&WS[(1 * 32 + dt * 16 + c) * 40 + g * 8];
        aH[dt] = *(const bh8*)&WS[(2 * 32 + dt * 16 + c) * 40 + g * 8];
    }

    for (int rr = lane; rr < 96; rr += 64) {
        int nb = rr >> 4, ml = rr & 15;
        int m = m0 + ml;
        int bg = bgraph[m * 6 + nb];
        bg = min(max(bg, 0), NM - 1);
        const float4* hr = (const float4*)(hbase + (size_t)bg * 32);
#pragma unroll
        for (int ii = 0; ii < 4; ii++) {
            float4 a = hr[2 * ii], b = hr[2 * ii + 1];
            us8 o;
            o[0] = f2b_bits(a.x); o[1] = f2b_bits(a.y); o[2] = f2b_bits(a.z); o[3] = f2b_bits(a.w);
            o[4] = f2b_bits(b.x); o[5] = f2b_bits(b.y); o[6] = f2b_bits(b.z); o[7] = f2b_bits(b.w);
            *(us8*)&hb[rr * 40 + ii * 8] = o;
        }
    }
    __builtin_amdgcn_wave_barrier();

    float r1v[2][4];
#pragma unroll
    for (int dt = 0; dt < 2; dt++)
#pragma unroll
        for (int r = 0; r < 4; r++)
            r1v[dt][r] = r1[(size_t)(ti * 32 + dt * 16 + 4 * g + r) * NM + m0 + c];

    const f32x4 zf = {0.f, 0.f, 0.f, 0.f};
    f32x4 sumA[2] = {zf, zf}, rhA[2] = {zf, zf};
    const int m = m0 + c;

    for (int nb = 0; nb < 6; nb++) {
        bh8 bfr = *(const bh8*)&hb[(nb * 16 + c) * 40 + g * 8];
        f32x4 c0 = __builtin_amdgcn_mfma_f32_16x16x32_bf16(aU[0], bfr, zf, 0, 0, 0);
        f32x4 c1 = __builtin_amdgcn_mfma_f32_16x16x32_bf16(aU[1], bfr, zf, 0, 0, 0);
        // own h rows in FULL f32 (L1-hot: gather touched these lines)
        int bg = bgraph[m * 6 + nb];
        bg = min(max(bg, 0), NM - 1);
        const float* hro = hbase + (size_t)bg * 32;
        f32x4 o0 = *(const f32x4*)&hro[4 * g];
        f32x4 o1 = *(const f32x4*)&hro[16 + 4 * g];
#pragma unroll
        for (int r = 0; r < 4; r++) {
            float rr0 = sigm(r1v[0][r] + c0[r]);
            float rr1 = sigm(r1v[1][r] + c1[r]);
            sumA[0][r] += o0[r];        sumA[1][r] += o1[r];
            rhA[0][r] += rr0 * o0[r];   rhA[1][r] += rr1 * o1[r];
        }
    }

    // split hi/lo sumh & rh for f32-accurate tail matmuls
    unsigned short* sSh = &SR[w][0];
    unsigned short* sSl = &SR[w][640];
    unsigned short* sRh = &SR[w][1280];
    unsigned short* sRl = &SR[w][1920];
#pragma unroll
    for (int dt = 0; dt < 2; dt++) {
        us4 oSh, oSl, oRh, oRl;
#pragma unroll
        for (int r = 0; r < 4; r++) {
            float sv = sumA[dt][r], rv = rhA[dt][r];
            unsigned short shh = f2b_bits(sv);
            oSh[r] = shh; oSl[r] = f2b_bits(sv - bb(shh));
            unsigned short rhh = f2b_bits(rv);
            oRh[r] = rhh; oRl[r] = f2b_bits(rv - bb(rhh));
        }
        int off = c * 40 + dt * 16 + 4 * g;
        *(us4*)&sSh[off] = oSh; *(us4*)&sSl[off] = oSl;
        *(us4*)&sRh[off] = oRh; *(us4*)&sRl[off] = oRl;
    }
    __builtin_amdgcn_wave_barrier();

    bh8 bSh = *(const bh8*)&sSh[c * 40 + g * 8];
    bh8 bSl = *(const bh8*)&sSl[c * 40 + g * 8];
    bh8 bRh = *(const bh8*)&sRh[c * 40 + g * 8];
    bh8 bRl = *(const bh8*)&sRl[c * 40 + g * 8];
    f32x4 z0 = __builtin_amdgcn_mfma_f32_16x16x32_bf16(aZ[0], bSh, zf, 0, 0, 0);
    z0 = __builtin_amdgcn_mfma_f32_16x16x32_bf16(aZ[0], bSl, z0, 0, 0, 0);
    f32x4 z1 = __builtin_amdgcn_mfma_f32_16x16x32_bf16(aZ[1], bSh, zf, 0, 0, 0);
    z1 = __builtin_amdgcn_mfma_f32_16x16x32_bf16(aZ[1], bSl, z1, 0, 0, 0);
    f32x4 p0 = __builtin_amdgcn_mfma_f32_16x16x32_bf16(aH[0], bRh, zf, 0, 0, 0);
    p0 = __builtin_amdgcn_mfma_f32_16x16x32_bf16(aH[0], bRl, p0, 0, 0, 0);
    f32x4 p1 = __builtin_amdgcn_mfma_f32_16x16x32_bf16(aH[1], bRh, zf, 0, 0, 0);
    p1 = __builtin_amdgcn_mfma_f32_16x16x32_bf16(aH[1], bRl, p1, 0, 0, 0);

    const float msk = (m == 0) ? 0.f : 1.f;
#pragma unroll
    for (int dt = 0; dt < 2; dt++) {
        f32x4 zt = dt ? z1 : z0;
        f32x4 pt = dt ? p1 : p0;
#pragma unroll
        for (int r = 0; r < 4; r++) {
            int d = dt * 16 + 4 * g + r;
            float zacc = az[(size_t)(ti * 32 + d) * NM + m] + zt[r];
            float pacc = ah[(size_t)(ti * 32 + d) * NM + m] + pt[r];
            float zz = sigm(zacc);
            float th = tanh_c(pacc);
            TB[w][c * 37 + d] = ((1.f - zz) * sumA[dt][r] + zz * th) * msk;
        }
    }
    __builtin_amdgcn_wave_barrier();
    float* ho = h_out + ((size_t)ti * NM + m0) * 32;
#pragma unroll
    for (int i = 0; i < 8; i++) {
        int idx = i * 64 + lane;
        ho[idx] = TB[w][(idx >> 5) * 37 + (idx & 31)];
    }
}

// ---------------- outs = relu([x, nei] @ Wo^T + b) * node_mask, scattered into qkv ----------------
// grid (NA/64, tch); block 256 = 64 atoms x 4 d-quarters
__global__ __launch_bounds__(256) void k_outs(
    const float* __restrict__ xT, const float* __restrict__ h,
    const int* __restrict__ agraph, const void* __restrict__ Wo_w, const void* __restrict__ Wo_b,
    int t0, float* __restrict__ qkv, const int* __restrict__ flag)
{
    int bf = *flag;
    const int ti = blockIdx.y, t = t0 + ti;
    const int hh = t / 3, s2 = t - 3 * hh;
    __shared__ float WL[32 * 297];
    __shared__ float tb[4][16 * 33];
    for (int i = threadIdx.x; i < 32 * 297; i += 256) {
        int d = i / 297, k = i - d * 297;
        WL[i] = (k < 288) ? ldw(Wo_w, ((size_t)t * 32 + d) * 288 + k, bf) : 0.f;
    }
    __syncthreads();
    const int q = threadIdx.x & 3, al = threadIdx.x >> 2;
    const int a = blockIdx.x * 64 + al;
    const int d0 = q * 8;
    float nei[32];
#pragma unroll
    for (int j = 0; j < 32; j++) nei[j] = 0.f;
#pragma unroll
    for (int nb = 0; nb < 6; nb++) {
        int ag = agraph[a * 6 + nb];
        ag = min(max(ag, 0), NM - 1);
        const float* hr = h + ((size_t)ti * NM + ag) * 32;
#pragma unroll
        for (int j4 = 0; j4 < 32; j4 += 4) {
            float4 v = *(const float4*)&hr[j4];
            nei[j4] += v.x; nei[j4 + 1] += v.y; nei[j4 + 2] += v.z; nei[j4 + 3] += v.w;
        }
    }
    float acc[8];
#pragma unroll
    for (int dd = 0; dd < 8; dd++) acc[dd] = ldw(Wo_b, t * 32 + d0 + dd, bf);
    for (int kc = 0; kc < 8; kc++) {
        float xv[32];
#pragma unroll
        for (int kk = 0; kk < 32; kk++) xv[kk] = xT[(size_t)(kc * 32 + kk) * NA + a];
#pragma unroll
        for (int dd = 0; dd < 8; dd++) {
            const float* wp = &WL[(d0 + dd) * 297 + kc * 32];
#pragma unroll
            for (int kk = 0; kk < 32; kk++) acc[dd] += xv[kk] * wp[kk];
        }
    }
    const int wv = threadIdx.x >> 6, l = threadIdx.x & 63, aw = al & 15;
#pragma unroll
    for (int dd = 0; dd < 8; dd++) {
        const float* wp = &WL[(d0 + dd) * 297 + 256];
        float s = acc[dd];
#pragma unroll
        for (int j = 0; j < 32; j++) s += nei[j] * wp[j];
        s = fmaxf(s, 0.f);
        if (a == 0) s = 0.f;
        tb[wv][aw * 33 + d0 + dd] = s;
    }
    __syncthreads();
    int abase = blockIdx.x * 64 + wv * 16;
#pragma unroll
    for (int i = 0; i < 8; i++) {
        int idx = i * 64 + l;
        int mm = idx >> 5, d = idx & 31;
        float v = tb[wv][mm * 33 + d];
        size_t dst;
        if (s2 == 0) dst = (size_t)(abase + mm) * 256 + hh * 32 + d;
        else dst = (size_t)s2 * 1048576 + (size_t)hh * 131072 + (size_t)(abase + mm) * 32 + d;
        qkv[dst] = v;
    }
}

// ---------------- per-molecule 32x32 attention block ----------------
__global__ __launch_bounds__(64) void k_attn_mol(
    const float* __restrict__ Qp, const float* __restrict__ Kp, const float* __restrict__ Vp,
    const int* __restrict__ scopes, float* __restrict__ ctx)
{
    int mol = blockIdx.x;
    int g = threadIdx.x >> 5;
    int head = blockIdx.y * 2 + g;
    int lane = threadIdx.x & 31;
    int start = scopes[2 * mol];
    int len = min(scopes[2 * mol + 1], 32);
    if (len <= 0) return;
    __shared__ float Ql[2][32 * 36], Kl[2][32 * 36], Vl[2][32 * 36], Pl[2][32 * 36];
    for (int i = 0; i < len; i++) {
        if (start + i >= NA) break;
        size_t base = (size_t)(start + i) * 256 + head * 32 + lane;
        Ql[g][i * 36 + lane] = Qp[base];
        Kl[g][i * 36 + lane] = Kp[base];
        Vl[g][i * 36 + lane] = Vp[base];
    }
    for (int i = len; i < 32; i++) { Vl[g][i * 36 + lane] = 0.f; Kl[g][i * 36 + lane] = 0.f; }
    float kreg[32];
#pragma unroll
    for (int d2 = 0; d2 < 32; d2++) kreg[d2] = Kl[g][lane * 36 + d2];
    const float scale = 0.17677669529663687f;
    for (int i = 0; i < len; i++) {
        float s = 0.f;
#pragma unroll
        for (int d2 = 0; d2 < 32; d2++) s += Ql[g][i * 36 + d2] * kreg[d2];
        s *= scale;
        if (lane >= len) s = -1e30f;
        float mx = s;
#pragma unroll
        for (int off = 16; off > 0; off >>= 1) mx = fmaxf(mx, __shfl_xor(mx, off, 32));
        float p = __expf(s - mx);
        if (lane >= len) p = 0.f;
        float sum = p;
#pragma unroll
        for (int off = 16; off > 0; off >>= 1) sum += __shfl_xor(sum, off, 32);
        Pl[g][i * 36 + lane] = p / sum;
    }
    for (int i = 0; i < len; i++) {
        if (start + i >= NA) break;
        float acc = 0.f;
#pragma unroll
        for (int j = 0; j < 32; j++) acc += Pl[g][i * 36 + j] * Vl[g][j * 36 + lane];
        ctx[(size_t)(start + i) * 256 + head * 32 + lane] = acc;
    }
}

// ---------------- column sums of Vp ----------------
__global__ __launch_bounds__(256) void k_colsum(
    const float* __restrict__ Vp, float* __restrict__ partial)
{
    int b = blockIdx.x, c = threadIdx.x;
    float a0 = 0.f, a1 = 0.f, a2 = 0.f, a3 = 0.f;
    for (int j = 0; j < 32; j++) {
        const float* rp = Vp + ((size_t)b * 128 + j * 4) * 256 + c;
        a0 += rp[0]; a1 += rp[256]; a2 += rp[512]; a3 += rp[768];
    }
    partial[b * 256 + c] = a0 + a1 + a2 + a3;
}

// ---------------- degenerate attention rows ----------------
__global__ __launch_bounds__(256) void k_fill(
    const float* __restrict__ Vp, const float* __restrict__ partial,
    const int* __restrict__ molid, float* __restrict__ ctx)
{
    int a = blockIdx.x, c = threadIdx.x;
    if (molid[a] >= 0) return;
    float v;
    if (a == 0) v = Vp[c];
    else {
        float s = 0.f;
#pragma unroll
        for (int b = 0; b < 32; b++) s += partial[b * 256 + c];
        v = s * (1.f / 4096.f);
    }
    ctx[(size_t)a * 256 + c] = v;
}

// ---------------- layernorm -> out ----------------
__global__ __launch_bounds__(256) void k_ln(
    const float* __restrict__ xo, const void* __restrict__ g_, const void* __restrict__ b_,
    void* __restrict__ out, const int* __restrict__ flag)
{
    int bf = *flag;
    int a = blockIdx.x, c = threadIdx.x;
    float v = xo[(size_t)a * 256 + c];
    __shared__ float red[4], red2[4];
    float s = v;
#pragma unroll
    for (int off = 32; off > 0; off >>= 1) s += __shfl_down(s, off);
    int w = threadIdx.x >> 6, ln2 = threadIdx.x & 63;
    if (ln2 == 0) red[w] = s;
    __syncthreads();
    float mu = (red[0] + red[1] + red[2] + red[3]) * (1.f / 256.f);
    float dv = v - mu;
    float sq = dv * dv;
#pragma unroll
    for (int off = 32; off > 0; off >>= 1) sq += __shfl_down(sq, off);
    if (ln2 == 0) red2[w] = sq;
    __syncthreads();
    float var = (red2[0] + red2[1] + red2[2] + red2[3]) * (1.f / 256.f);
    float y = dv * rsqrtf(var + 1e-5f) * ldw(g_, c, bf) + ldw(b_, c, bf);
    size_t idx = (size_t)a * 256 + c;
    if (bf) ((bf16*)out)[idx] = f2b(y);
    else    ((float*)out)[idx] = y;
}

extern "C" void kernel_launch(void* const* d_in, const int* in_sizes, int n_in,
                              void* d_out, int out_size, void* d_ws, size_t ws_size,
                              hipStream_t stream)
{
    const void* fnode  = d_in[0];
    const void* fmess  = d_in[1];
    const int*  agraph = (const int*)d_in[2];
    const int*  bgraph = (const int*)d_in[3];
    const int*  scopes = (const int*)d_in[4];
    const void* W_i_w  = d_in[5];
    const void* Wz_w   = d_in[6];
    const void* Wz_b   = d_in[7];
    const void* Wr_w   = d_in[8];
    const void* Ur_w   = d_in[9];
    const void* Ur_b   = d_in[10];
    const void* Wh_w   = d_in[11];
    const void* Wh_b   = d_in[12];
    const void* Wo_w   = d_in[13];
    const void* Wo_b   = d_in[14];
    const void* attn_w = d_in[15];
    const void* attn_b = d_in[16];
    const void* aow    = d_in[17];
    const void* bww    = d_in[18];
    const void* ln_g   = d_in[19];
    const void* ln_b   = d_in[20];
    int nmol = in_sizes[4] / 2;

    // -------- workspace layout (f32 units); tch chosen from ws_size --------
    const size_t REGA  = 4718592;   // hmB hi/lo (36*NM*16 u16) early; ctx/y1/xo (3.15M f32) late
    const size_t PACKF = 16384 + 98304 + 32768 + 32768 + 331776;   // 512000 f32-equiv
    const size_t fixedF = 1048576 + REGA + 3 * 1048576 + NA + 1 + 32 * 256 + PACKF;
    int tch = 2;
    if (ws_size / 4 >= fixedF + 5ull * 8 * 32 * NM + 1024) tch = 8;
    else if (ws_size / 4 >= fixedF + 5ull * 4 * 32 * NM + 1024) tch = 4;
    const size_t CS = (size_t)tch * 32 * NM;

    float* p   = (float*)d_ws;
    float* xT  = p;                    p += 1048576;
    float* regA = p;                   p += REGA;
    float* cs  = p;                    p += 5 * CS;
    float* qkv = p;                    p += 3 * 1048576;
    int*   molid = (int*)p;            p += NA;
    int*   dflag = (int*)p;            p += 1;
    float* partial = p;                p += 32 * 256;
    unsigned short* wpk_wi   = (unsigned short*)p;  p += 16384;    // 256x128
    unsigned short* wpk_attn = (unsigned short*)p;  p += 98304;    // 768x256
    unsigned short* wpk_aow  = (unsigned short*)p;  p += 32768;    // 256x256
    unsigned short* wpk_bww  = (unsigned short*)p;  p += 32768;    // 256x256
    unsigned short* gpack    = (unsigned short*)p;  p += 331776;   // 3x768x288

    unsigned short* hmB = (unsigned short*)regA;
    float* ctx = regA;
    float* y1  = regA + 1048576;
    float* xo  = regA + 2097152;

    float* r1 = cs;
    float* az = cs + CS;
    float* ah = cs + 2 * CS;
    float* h0 = cs + 3 * CS;
    float* h1 = cs + 4 * CS;
    float* fnode_f = qkv;              // 4096x128 padded (524288)
    float* x       = qkv + 524288;
    float* Qp  = cs;
    float* Kp  = cs + 1048576;
    float* Vp  = cs + 2097152;

    k_flag<<<1, 64, 0, stream>>>(fnode, dflag);

    // weight packs (bf16, fragment-aligned)
    k_wpack<<<768, 256, 0, stream>>>(Wr_w, 262, 262, 288, gpack, dflag);
    k_wpack<<<768, 256, 0, stream>>>(Wz_w, 294, 262, 288, gpack + 768 * 288, dflag);
    k_wpack<<<768, 256, 0, stream>>>(Wh_w, 294, 262, 288, gpack + 2 * 768 * 288, dflag);
    k_wpack<<<256, 256, 0, stream>>>(W_i_w, 98, 98, 128, wpk_wi, dflag);
    k_wpack<<<768, 256, 0, stream>>>(attn_w, 256, 256, 256, wpk_attn, dflag);
    k_wpack<<<256, 256, 0, stream>>>(aow, 256, 256, 256, wpk_aow, dflag);
    k_wpack<<<256, 256, 0, stream>>>(bww, 256, 256, 256, wpk_bww, dflag);

    k_cast_pad<<<(NA * 128) / 256, 256, 0, stream>>>(fnode, fnode_f, dflag);
    k_gemm_m<<<dim3(NA / 64, 2), 256, 0, stream>>>(fnode_f, wpk_wi, nullptr, 0, 0, x, 4, dflag);
    k_xpose<<<dim3(128, 8), 256, 0, stream>>>(x, xT);
    k_hmess_b<<<dim3(NM / 32, 9), 256, 0, stream>>>(x, fmess, hmB, dflag);
    k_molmap<<<(NA + 255) / 256, 256, 0, stream>>>(scopes, nmol, molid);

    for (int tc = 0; tc < 24 / tch; tc++) {
        int t0 = tc * tch;
        k_pre_mfma<<<dim3(NM / 128, tch), 256, 0, stream>>>(
            hmB, gpack, Ur_b, Wz_b, Wh_b, t0, r1, az, ah, h1, dflag);
        k_step_m<<<dim3(NM / 64, tch), 256, 0, stream>>>(h1, h0, r1, az, ah, bgraph, Ur_w, Wz_w, Wh_w, t0, dflag);
        k_step_m<<<dim3(NM / 64, tch), 256, 0, stream>>>(h0, h1, r1, az, ah, bgraph, Ur_w, Wz_w, Wh_w, t0, dflag);
        k_outs<<<dim3(NA / 64, tch), 256, 0, stream>>>(xT, h1, agraph, Wo_w, Wo_b, t0, qkv, dflag);
    }

    k_gemm_m<<<dim3(NA / 64, 2), 256, 0, stream>>>(qkv,           wpk_attn,          attn_b, 0,   1, Qp, 8, dflag);
    k_gemm_m<<<dim3(NA / 64, 2), 256, 0, stream>>>(qkv + 1048576, wpk_attn + 65536,  attn_b, 256, 1, Kp, 8, dflag);
    k_gemm_m<<<dim3(NA / 64, 2), 256, 0, stream>>>(qkv + 2097152, wpk_attn + 131072, attn_b, 512, 1, Vp, 8, dflag);

    k_attn_mol<<<dim3(nmol, 4), 64, 0, stream>>>(Qp, Kp, Vp, scopes, ctx);
    k_colsum<<<32, 256, 0, stream>>>(Vp, partial);
    k_fill<<<NA, 256, 0, stream>>>(Vp, partial, molid, ctx);

    k_gemm_m<<<dim3(NA / 64, 2), 256, 0, stream>>>(ctx, wpk_aow, nullptr, 0, 0, y1, 8, dflag);
    k_gemm_m<<<dim3(NA / 64, 2), 256, 0, stream>>>(y1,  wpk_bww, nullptr, 0, 0, xo, 8, dflag);
    k_ln<<<NA, 256, 0, stream>>>(xo, ln_g, ln_b, d_out, dflag);
    (void)ws_size; (void)out_size; (void)n_in;
}